// Round 4
// baseline (27413.074 us; speedup 1.0000x reference)
//
#include <hip/hip_runtime.h>
#include <hip/hip_bf16.h>
#include <cstdint>
#include <cstddef>

// ---------- types & helpers ----------
typedef __attribute__((ext_vector_type(8))) short bf8v;   // 8 x bf16 (raw bits)
typedef __attribute__((ext_vector_type(4))) float f4v;

__device__ __forceinline__ float bf2f(unsigned short u) {
  union { unsigned int i; float f; } v; v.i = ((unsigned int)u) << 16; return v.f;
}
__device__ __forceinline__ unsigned short f2bf(float f) {
  union { float fl; unsigned int i; } v; v.fl = f;
  return (unsigned short)((v.i + 0x7FFFu + ((v.i >> 16) & 1u)) >> 16);
}
__device__ __forceinline__ void gload_lds16(const void* gsrc, void* ldst) {
  __builtin_amdgcn_global_load_lds(
      (const __attribute__((address_space(1))) unsigned int*)gsrc,
      (__attribute__((address_space(3))) unsigned int*)ldst, 16, 0, 0);
}

// ---------- prep kernels ----------
__global__ void cast_bf16_kernel(const float* __restrict__ in, unsigned short* __restrict__ out, int n) {
  int i = blockIdx.x * 256 + threadIdx.x;
  if (i < n) out[i] = f2bf(in[i]);
}

// W: [T][F][O] f32  ->  Wt: [T*O][F] bf16   (row n = t*O+o, col f)
__global__ void transpose_cast_kernel(const float* __restrict__ W, unsigned short* __restrict__ Wt,
                                      int F, int O, int n) {
  int idx = blockIdx.x * 256 + threadIdx.x;
  if (idx >= n) return;
  int f  = idx % F;
  int no = idx / F;
  int k = no / O, o = no % O;
  Wt[idx] = f2bf(W[((size_t)k * F + f) * O + o]);
}

// ---------- embedding -> emb bf16, s-major: emb[(s*96 + r)*512 + o] ----------
__global__ __launch_bounds__(256) void embed_kernel(const float* __restrict__ inp,
                                                    const int* __restrict__ ptypes,
                                                    const float* __restrict__ embW,
                                                    const float* __restrict__ embB,
                                                    unsigned short* __restrict__ emb) {
  int r = blockIdx.x;          // 0..95  (b*6 + a)
  int st = blockIdx.y;         // 0..31  (s tile of 16)
  int b = r / 6, a = r % 6;
  int t = ptypes[r];
  __shared__ float vec[16][102];
  int tid = threadIdx.x;
  for (int i = tid; i < 16 * 102; i += 256) {
    int sl = i / 102, k = i - sl * 102;
    const float* row = inp + ((size_t)(b * 512 + st * 16 + sl)) * 520;
    vec[sl][k] = (k < 72) ? row[30 + a * 73 + 1 + k] : row[k - 72];
  }
  __syncthreads();
  int o0 = tid * 2;
  float acc[16][2];
#pragma unroll
  for (int s = 0; s < 16; ++s) { acc[s][0] = 0.f; acc[s][1] = 0.f; }
  const float* W = embW + (size_t)t * 102 * 512;
  for (int k = 0; k < 102; ++k) {
    float2 w = *(const float2*)&W[k * 512 + o0];
#pragma unroll
    for (int s = 0; s < 16; ++s) {
      float v = vec[s][k];
      acc[s][0] += v * w.x; acc[s][1] += v * w.y;
    }
  }
  float b0v = embB[t * 512 + o0], b1v = embB[t * 512 + o0 + 1];
#pragma unroll
  for (int s = 0; s < 16; ++s) {
    float v0 = fmaxf(acc[s][0] + b0v, 0.f);
    float v1 = fmaxf(acc[s][1] + b1v, 0.f);
    size_t m = ((size_t)(st * 16 + s) * 96 + r) * 512 + o0;
    emb[m] = f2bf(v0); emb[m + 1] = f2bf(v1);
  }
}

// ---------- MFMA bt-GEMM: C[M,N] = A[M,K](bf16) @ B[N,K](bf16)^T (+bias) ----------
template<bool OUT_BF16, bool ADD_BIAS>
__global__ __launch_bounds__(256)
void gemm_bt(const unsigned short* __restrict__ A, const unsigned short* __restrict__ B,
             void* __restrict__ C, const float* __restrict__ bias, int M, int N, int K) {
  __shared__ __align__(16) unsigned short As[128 * 64];
  __shared__ __align__(16) unsigned short Bs[128 * 64];
  const int tid = threadIdx.x;
  const int wave = tid >> 6, lane = tid & 63;
  const int bm = blockIdx.x, bn = blockIdx.y;
  const int wm = (wave >> 1) * 64, wn = (wave & 1) * 64;
  const int lr = lane >> 3, lc = lane & 7;
  f4v acc[4][4];
#pragma unroll
  for (int i = 0; i < 4; ++i)
#pragma unroll
    for (int j = 0; j < 4; ++j) acc[i][j] = (f4v){0.f, 0.f, 0.f, 0.f};
  const unsigned short* Ab = A + (size_t)bm * 128 * K;
  const unsigned short* Bb = B + (size_t)bn * 128 * K;
  const int arow = wave * 32;

  for (int k0 = 0; k0 < K; k0 += 64) {
#pragma unroll
    for (int i = 0; i < 4; ++i) {
      int row = arow + i * 8 + lr;
      gload_lds16(Ab + (size_t)row * K + k0 + lc * 8, &As[(arow + i * 8) * 64]);
      gload_lds16(Bb + (size_t)row * K + k0 + lc * 8, &Bs[(arow + i * 8) * 64]);
    }
    __syncthreads();
#pragma unroll
    for (int kk = 0; kk < 64; kk += 32) {
      bf8v af[4], bv[4];
#pragma unroll
      for (int mi = 0; mi < 4; ++mi)
        af[mi] = *(const bf8v*)&As[(wm + mi * 16 + (lane & 15)) * 64 + kk + (lane >> 4) * 8];
#pragma unroll
      for (int ni = 0; ni < 4; ++ni)
        bv[ni] = *(const bf8v*)&Bs[(wn + ni * 16 + (lane & 15)) * 64 + kk + (lane >> 4) * 8];
#pragma unroll
      for (int mi = 0; mi < 4; ++mi)
#pragma unroll
        for (int ni = 0; ni < 4; ++ni)
          acc[mi][ni] = __builtin_amdgcn_mfma_f32_16x16x32_bf16(af[mi], bv[ni], acc[mi][ni], 0, 0, 0);
    }
    __syncthreads();
  }
  const int r0 = (lane >> 4) * 4, c0 = lane & 15;
#pragma unroll
  for (int mi = 0; mi < 4; ++mi)
#pragma unroll
    for (int ni = 0; ni < 4; ++ni) {
      int col = bn * 128 + wn + ni * 16 + c0;
      float bvv = ADD_BIAS ? bias[col] : 0.f;
#pragma unroll
      for (int j = 0; j < 4; ++j) {
        size_t row = (size_t)bm * 128 + wm + mi * 16 + r0 + j;
        float v = acc[mi][ni][j] + bvv;
        if (OUT_BF16) ((unsigned short*)C)[row * N + col] = f2bf(v);
        else          ((float*)C)[row * N + col] = v;
      }
    }
}

// ---------- persistent GRU chunk: 6 independent 16-row groups x 64 j-blocks ----------
// 384 blocks x 256 threads. g = blockIdx%6 owns rows [g*16,+16); jb = blockIdx/6 owns j [jb*16,+16) x 3 gates.
// Wave wv owns K-slice [wv*256,+256). h staged coalesced into LDS per block.
__global__ __launch_bounds__(256, 1) void gru_chunk(const unsigned short* __restrict__ Whh_bf,
                                                    const float* __restrict__ gxc,
                                                    const float* __restrict__ bhh,
                                                    unsigned short* __restrict__ h_bf,
                                                    float* __restrict__ h_f32,
                                                    unsigned short* __restrict__ gnn,
                                                    int s_base, int* __restrict__ bar) {
  const int tid = threadIdx.x, lane = tid & 63, wv = tid >> 6;
  const int g  = blockIdx.x % 6;
  const int jb = blockIdx.x / 6;
  const int j0 = jb * 16;
  const int l15 = lane & 15, lhi = lane >> 4;
  const int r0g = g * 16;

  // resident weights: 3 gates x 8 kk (B-operand rows = j0+l15)
  bf8v wfrag[3][8];
#pragma unroll
  for (int gg = 0; gg < 3; ++gg)
#pragma unroll
    for (int kk = 0; kk < 8; ++kk)
      wfrag[gg][kk] = *(const bf8v*)&Whh_bf[((size_t)(gg * 1024 + j0 + l15)) * 1024 + wv * 256 + kk * 32 + lhi * 8];

  const int r_l = tid >> 4;     // 0..15
  const int j_l = tid & 15;
  float hreg = h_f32[(size_t)(r0g + r_l) * 1024 + j0 + j_l];
  const float bh0 = bhh[j0 + j_l], bh1 = bhh[1024 + j0 + j_l], bh2 = bhh[2048 + j0 + j_l];

  __shared__ __align__(16) unsigned short h_lds[16 * 1032];   // padded rows (pitch 1032)
  __shared__ __align__(16) float red[4][16][52];

  int* arr = bar + g * 32;
  int* rel = bar + g * 32 + 16;
  int gen = s_base;

  for (int sl = 0; sl < 32; ++sl) {
    const unsigned short* hb = h_bf + (size_t)(sl & 1) * 98304;
    unsigned short* hbn      = h_bf + (size_t)((sl & 1) ^ 1) * 98304;

    // prefetch gx (independent of h)
    size_t gxi = ((size_t)(sl * 96 + r0g + r_l)) * 3072 + j0 + j_l;
    float xr = gxc[gxi], xz = gxc[gxi + 1024], xn = gxc[gxi + 2048];

    // stage this group's 16 h-rows into LDS, coalesced (wave wv: rows wv*4..+4)
#pragma unroll
    for (int rr = 0; rr < 4; ++rr) {
      int row = wv * 4 + rr;
      const unsigned short* src = hb + (size_t)(r0g + row) * 1024;
      gload_lds16(src + lane * 8,       &h_lds[row * 1032]);
      gload_lds16(src + 512 + lane * 8, &h_lds[row * 1032 + 512]);
    }
    __syncthreads();   // compiler drains vmcnt before barrier

    f4v acc0 = (f4v){0.f,0.f,0.f,0.f}, acc1 = acc0, acc2 = acc0;
#pragma unroll
    for (int kk = 0; kk < 8; ++kk) {
      bf8v a = *(const bf8v*)&h_lds[l15 * 1032 + wv * 256 + kk * 32 + lhi * 8];
      acc0 = __builtin_amdgcn_mfma_f32_16x16x32_bf16(a, wfrag[0][kk], acc0, 0, 0, 0);
      acc1 = __builtin_amdgcn_mfma_f32_16x16x32_bf16(a, wfrag[1][kk], acc1, 0, 0, 0);
      acc2 = __builtin_amdgcn_mfma_f32_16x16x32_bf16(a, wfrag[2][kk], acc2, 0, 0, 0);
    }

    // K-partials to LDS: C layout row(m)=lhi*4+jj (h-row), col(n)=l15 (j)
#pragma unroll
    for (int jj = 0; jj < 4; ++jj) {
      red[wv][lhi * 4 + jj][l15]      = acc0[jj];
      red[wv][lhi * 4 + jj][16 + l15] = acc1[jj];
      red[wv][lhi * 4 + jj][32 + l15] = acc2[jj];
    }
    __syncthreads();

    float gr = red[0][r_l][j_l]      + red[1][r_l][j_l]      + red[2][r_l][j_l]      + red[3][r_l][j_l]      + bh0;
    float gz = red[0][r_l][16 + j_l] + red[1][r_l][16 + j_l] + red[2][r_l][16 + j_l] + red[3][r_l][16 + j_l] + bh1;
    float gn = red[0][r_l][32 + j_l] + red[1][r_l][32 + j_l] + red[2][r_l][32 + j_l] + red[3][r_l][32 + j_l] + bh2;
    float rg = 1.f / (1.f + expf(-(xr + gr)));
    float zg = 1.f / (1.f + expf(-(xz + gz)));
    float ng = tanhf(xn + rg * gn);
    hreg = (1.f - zg) * ng + zg * hreg;
    unsigned short hb16 = f2bf(hreg);
    int r = r0g + r_l;
    hbn[(size_t)r * 1024 + j0 + j_l] = hb16;
    int bb = r / 6, aa = r - bb * 6;
    gnn[(((size_t)bb * 512 + s_base + sl) * 6 + aa) * 1024 + j0 + j_l] = hb16;

    // per-group device barrier (64 participants)
    __syncthreads();
    if (tid == 0) {
      __threadfence();
      int a = __hip_atomic_fetch_add(arr, 1, __ATOMIC_ACQ_REL, __HIP_MEMORY_SCOPE_AGENT);
      if (a == 63) {
        __hip_atomic_store(arr, 0, __ATOMIC_RELAXED, __HIP_MEMORY_SCOPE_AGENT);
        __hip_atomic_fetch_add(rel, 1, __ATOMIC_ACQ_REL, __HIP_MEMORY_SCOPE_AGENT);
      } else {
        while (__hip_atomic_load(rel, __ATOMIC_ACQUIRE, __HIP_MEMORY_SCOPE_AGENT) <= gen) {}
      }
      __threadfence();
    }
    gen++;
    __syncthreads();
  }

  h_f32[(size_t)(r0g + r_l) * 1024 + j0 + j_l] = hreg;
}

// ---------- GAT0 attention+combine (chunk-local bs) ----------
__global__ __launch_bounds__(256) void gat0_combine(const unsigned short* __restrict__ Wh,
                                                    const float* __restrict__ a0,
                                                    unsigned short* __restrict__ g0) {
  int bs = blockIdx.x;
  __shared__ __align__(16) float W[6][1024];
  int tid = threadIdx.x;
  const unsigned short* src = Wh + (size_t)bs * 6144;
  for (int i = tid; i < 768; i += 256) {
    bf8v v = ((const bf8v*)src)[i];
    float* dst = &W[0][0] + i * 8;
#pragma unroll
    for (int j = 0; j < 8; ++j) dst[j] = bf2f((unsigned short)v[j]);
  }
  __syncthreads();
  int k = tid >> 6, l = tid & 63;
  float ai[4], aj[4];
#pragma unroll
  for (int i = 0; i < 4; ++i) { ai[i] = a0[k * 512 + l + i * 64]; aj[i] = a0[k * 512 + 256 + l + i * 64]; }
  float ei[6], ej[6];
#pragma unroll
  for (int n = 0; n < 6; ++n) {
    float pi = 0.f, pj = 0.f;
#pragma unroll
    for (int i = 0; i < 4; ++i) { float w = W[n][k * 256 + l + i * 64]; pi += w * ai[i]; pj += w * aj[i]; }
    for (int off = 32; off; off >>= 1) { pi += __shfl_xor(pi, off); pj += __shfl_xor(pj, off); }
    ei[n] = pi; ej[n] = pj;
  }
  float attn[6][6];
#pragma unroll
  for (int n = 0; n < 6; ++n) {
    float e[6]; float mx = -1e30f;
#pragma unroll
    for (int m = 0; m < 6; ++m) { e[m] = fmaxf(ei[n] + ej[m], 0.f); mx = fmaxf(mx, e[m]); }
    float ssum = 0.f;
#pragma unroll
    for (int m = 0; m < 6; ++m) { e[m] = expf(e[m] - mx); ssum += e[m]; }
    float inv = 1.f / ssum;
#pragma unroll
    for (int m = 0; m < 6; ++m) attn[n][m] = e[m] * inv;
  }
#pragma unroll
  for (int n = 0; n < 6; ++n)
#pragma unroll
    for (int i = 0; i < 4; ++i) {
      int o = l + i * 64;
      float accv = 0.f;
#pragma unroll
      for (int m = 0; m < 6; ++m) accv += attn[n][m] * W[m][k * 256 + o];
      float v = accv > 0.f ? accv : expm1f(accv);
      g0[((size_t)bs * 6 + n) * 1024 + k * 256 + o] = f2bf(v);
    }
}

// ---------- GAT1 attention+combine, node0 only -> featc bf16 ----------
__global__ __launch_bounds__(256) void gat1_combine(const unsigned short* __restrict__ Wh,
                                                    const float* __restrict__ a1,
                                                    unsigned short* __restrict__ feat0) {
  int bs = blockIdx.x;
  __shared__ __align__(16) float W[6][512];
  int tid = threadIdx.x;
  const unsigned short* src = Wh + (size_t)bs * 3072;
  for (int i = tid; i < 384; i += 256) {
    bf8v v = ((const bf8v*)src)[i];
    float* dst = &W[0][0] + i * 8;
#pragma unroll
    for (int j = 0; j < 8; ++j) dst[j] = bf2f((unsigned short)v[j]);
  }
  __syncthreads();
  int k = tid >> 6, l = tid & 63;
  float ai[2], aj[2];
#pragma unroll
  for (int i = 0; i < 2; ++i) { ai[i] = a1[k * 256 + l + i * 64]; aj[i] = a1[k * 256 + 128 + l + i * 64]; }
  float pi = 0.f;
#pragma unroll
  for (int i = 0; i < 2; ++i) pi += W[0][k * 128 + l + i * 64] * ai[i];
  for (int off = 32; off; off >>= 1) pi += __shfl_xor(pi, off);
  float ei0 = pi;
  float ej[6];
#pragma unroll
  for (int m = 0; m < 6; ++m) {
    float pj = 0.f;
#pragma unroll
    for (int i = 0; i < 2; ++i) pj += W[m][k * 128 + l + i * 64] * aj[i];
    for (int off = 32; off; off >>= 1) pj += __shfl_xor(pj, off);
    ej[m] = pj;
  }
  float e[6]; float mx = -1e30f;
#pragma unroll
  for (int m = 0; m < 6; ++m) { e[m] = fmaxf(ei0 + ej[m], 0.f); mx = fmaxf(mx, e[m]); }
  float ssum = 0.f;
#pragma unroll
  for (int m = 0; m < 6; ++m) { e[m] = expf(e[m] - mx); ssum += e[m]; }
  float inv = 1.f / ssum;
#pragma unroll
  for (int i = 0; i < 2; ++i) {
    int o = l + i * 64;
    float accv = 0.f;
#pragma unroll
    for (int m = 0; m < 6; ++m) accv += (e[m] * inv) * W[m][k * 128 + o];
    float v = accv > 0.f ? accv : expm1f(accv);
    feat0[(size_t)bs * 512 + k * 128 + o] = f2bf(v);
  }
}

// ---------- actor GEMM1 (MFMA): h1 = relu(featc @ aW1[t0]^T + ab1[t0]) -> bf16 ----------
__global__ __launch_bounds__(256)
void gemm_head(const unsigned short* __restrict__ A, const unsigned short* __restrict__ Wt5,
               const float* __restrict__ bias5, const int* __restrict__ ptypes, int b0,
               unsigned short* __restrict__ C) {
  __shared__ __align__(16) unsigned short As[128 * 64];
  __shared__ __align__(16) unsigned short Bs[128 * 64];
  const int tid = threadIdx.x;
  const int wave = tid >> 6, lane = tid & 63;
  const int bm = blockIdx.x, bn = blockIdx.y;       // (96, 2): M=12288, N=256, K=512
  const int t0 = ptypes[(b0 + (bm >> 2)) * 6];
  const unsigned short* B = Wt5 + (size_t)t0 * 256 * 512;
  const float* bias = bias5 + t0 * 256;
  const int K = 512, N = 256;
  const int wm = (wave >> 1) * 64, wn = (wave & 1) * 64;
  const int lr = lane >> 3, lc = lane & 7;
  f4v acc[4][4];
#pragma unroll
  for (int i = 0; i < 4; ++i)
#pragma unroll
    for (int j = 0; j < 4; ++j) acc[i][j] = (f4v){0.f, 0.f, 0.f, 0.f};
  const unsigned short* Ab = A + (size_t)bm * 128 * K;
  const unsigned short* Bb = B + (size_t)bn * 128 * K;
  const int arow = wave * 32;

  for (int k0 = 0; k0 < K; k0 += 64) {
#pragma unroll
    for (int i = 0; i < 4; ++i) {
      int row = arow + i * 8 + lr;
      gload_lds16(Ab + (size_t)row * K + k0 + lc * 8, &As[(arow + i * 8) * 64]);
      gload_lds16(Bb + (size_t)row * K + k0 + lc * 8, &Bs[(arow + i * 8) * 64]);
    }
    __syncthreads();
#pragma unroll
    for (int kk = 0; kk < 64; kk += 32) {
      bf8v af[4], bv[4];
#pragma unroll
      for (int mi = 0; mi < 4; ++mi)
        af[mi] = *(const bf8v*)&As[(wm + mi * 16 + (lane & 15)) * 64 + kk + (lane >> 4) * 8];
#pragma unroll
      for (int ni = 0; ni < 4; ++ni)
        bv[ni] = *(const bf8v*)&Bs[(wn + ni * 16 + (lane & 15)) * 64 + kk + (lane >> 4) * 8];
#pragma unroll
      for (int mi = 0; mi < 4; ++mi)
#pragma unroll
        for (int ni = 0; ni < 4; ++ni)
          acc[mi][ni] = __builtin_amdgcn_mfma_f32_16x16x32_bf16(af[mi], bv[ni], acc[mi][ni], 0, 0, 0);
    }
    __syncthreads();
  }
  const int r0 = (lane >> 4) * 4, c0 = lane & 15;
#pragma unroll
  for (int mi = 0; mi < 4; ++mi)
#pragma unroll
    for (int ni = 0; ni < 4; ++ni) {
      int col = bn * 128 + wn + ni * 16 + c0;
      float bvv = bias[col];
#pragma unroll
      for (int j = 0; j < 4; ++j) {
        size_t row = (size_t)bm * 128 + wm + mi * 16 + r0 + j;
        C[row * N + col] = f2bf(fmaxf(acc[mi][ni][j] + bvv, 0.f));
      }
    }
}

// ---------- actor GEMM2: logits = h1 @ aW2[t0] + ab2[t0], masked ----------
__global__ __launch_bounds__(256) void actor2_kernel(const unsigned short* __restrict__ h1c,
                                                     const int* __restrict__ ptypes,
                                                     const float* __restrict__ aW2, const float* __restrict__ ab2,
                                                     const float* __restrict__ inp, float* __restrict__ out, int b0) {
  int bl = blockIdx.x, st = blockIdx.y;   // (4, 32)
  int b = b0 + bl;
  int t0 = ptypes[b * 6];
  __shared__ float h1[16][260];
  int tid = threadIdx.x;
  const unsigned short* src = h1c + ((size_t)bl * 512 + st * 16) * 256;
  for (int i = tid; i < 512; i += 256) {
    bf8v v = ((const bf8v*)src)[i];
    int r = (i * 8) >> 8, c = (i * 8) & 255;
#pragma unroll
    for (int j = 0; j < 8; ++j) h1[r][c + j] = bf2f((unsigned short)v[j]);
  }
  __syncthreads();
  const float* W2p = aW2 + (size_t)t0 * 256 * 52;
  for (int idx = tid; idx < 16 * 52; idx += 256) {
    int s = idx / 52, d = idx - s * 52;
    float a = ab2[t0 * 52 + d];
    for (int i = 0; i < 256; ++i) a += h1[s][i] * W2p[i * 52 + d];
    int sg = st * 16 + s;
    float m = inp[((size_t)b * 512 + sg) * 520 + 468 + d];
    out[((size_t)b * 512 + sg) * 52 + d] = (m != 0.f) ? a : 0.f;
  }
}

// ---------- launch ----------
extern "C" void kernel_launch(void* const* d_in, const int* in_sizes, int n_in,
                              void* d_out, int out_size, void* d_ws, size_t ws_size,
                              hipStream_t stream) {
  const float* inputs = (const float*)d_in[0];
  const float* state  = (const float*)d_in[1];
  const int*   ptypes = (const int*)d_in[2];
  const float* emb_W  = (const float*)d_in[3];
  const float* emb_b  = (const float*)d_in[4];
  const float* W_ih   = (const float*)d_in[5];
  const float* W_hh   = (const float*)d_in[6];
  const float* b_ih   = (const float*)d_in[7];
  const float* b_hh   = (const float*)d_in[8];
  const float* W0     = (const float*)d_in[9];
  const float* a0     = (const float*)d_in[10];
  const float* W1     = (const float*)d_in[11];
  const float* a1     = (const float*)d_in[12];
  const float* aW1    = (const float*)d_in[13];
  const float* ab1    = (const float*)d_in[14];
  const float* aW2    = (const float*)d_in[15];
  const float* ab2    = (const float*)d_in[16];

  char* ws = (char*)d_ws;
  // phase A/B (peak ~203.4 MB, proven-safe region)
  unsigned short* emb    = (unsigned short*)(ws + 0);            // 50,331,648 B  [s][r][512] bf16
  float*          gxc    = (float*)(ws + 50331648);              // 37,748,736 B  32-step chunk, f32
  unsigned short* gnn    = (unsigned short*)(ws + 88080384);     // 100,663,296 B
  float*          h_f32  = (float*)(ws + 188743680);             // 393,216 B
  unsigned short* h_bf   = (unsigned short*)(ws + 189136896);    // 393,216 B (2 bufs)
  unsigned short* Wihb   = (unsigned short*)(ws + 189530112);    // 3,145,728 B
  unsigned short* W0t    = (unsigned short*)(ws + 192675840);    // 2,097,152 B
  unsigned short* W1t    = (unsigned short*)(ws + 194772992);    // 1,048,576 B
  unsigned short* Whh_bf = (unsigned short*)(ws + 195821568);    // 6,291,456 B
  unsigned short* aW1t   = (unsigned short*)(ws + 202113024);    // 1,310,720 B
  int*            bar    = (int*)(ws + 203423744);               // 1024 B -> end 203,424,768
  // GAT-phase chunk overlays in [0, 88,080,384) (emb+gxc dead)
  unsigned short* Wh0c  = (unsigned short*)(ws + 0);             // 25,165,824 B
  unsigned short* g0c   = (unsigned short*)(ws + 25165824);      // 25,165,824 B
  unsigned short* Wh1c  = (unsigned short*)(ws + 50331648);      // 12,582,912 B
  unsigned short* featc = (unsigned short*)(ws + 62914560);      // 12,582,912 B
  unsigned short* h1c   = (unsigned short*)(ws + 75497472);      //  6,291,456 B -> end 81,788,928

  float* logits = (float*)d_out;
  float* hfin   = (float*)d_out + 16 * 512 * 52;

  // prep
  cast_bf16_kernel<<<6144, 256, 0, stream>>>(W_ih, Wihb, 3072 * 512);
  cast_bf16_kernel<<<12288, 256, 0, stream>>>(W_hh, Whh_bf, 3072 * 1024);
  transpose_cast_kernel<<<4096, 256, 0, stream>>>(W0, W0t, 1024, 256, 4 * 1024 * 256);
  transpose_cast_kernel<<<2048, 256, 0, stream>>>(W1, W1t, 1024, 128, 4 * 1024 * 128);
  transpose_cast_kernel<<<2560, 256, 0, stream>>>(aW1, aW1t, 512, 256, 5 * 256 * 512);
  cast_bf16_kernel<<<384, 256, 0, stream>>>(state, h_bf, 96 * 1024);
  hipMemcpyAsync(h_f32, state, 96 * 1024 * sizeof(float), hipMemcpyDeviceToDevice, stream);
  hipMemsetAsync(bar, 0, 1024, stream);

  embed_kernel<<<dim3(96, 32), 256, 0, stream>>>(inputs, ptypes, emb_W, emb_b, emb);

  // GRU: 16 chunks of 32 steps
  for (int c = 0; c < 16; ++c) {
    gemm_bt<false, true><<<dim3(24, 24), 256, 0, stream>>>(
        emb + (size_t)c * 3072 * 512, Wihb, gxc, b_ih, 3072, 3072, 512);
    gru_chunk<<<384, 256, 0, stream>>>(Whh_bf, gxc, b_hh, h_bf, h_f32, gnn, c * 32, bar);
  }

  // GAT + actor: 4 b-chunks of 4 batches (12288 rows)
  for (int gc = 0; gc < 4; ++gc) {
    const size_t row0 = (size_t)gc * 12288;
    gemm_bt<true, false><<<dim3(96, 8), 256, 0, stream>>>(gnn + row0 * 1024, W0t, Wh0c, nullptr, 12288, 1024, 1024);
    gat0_combine<<<2048, 256, 0, stream>>>(Wh0c, a0, g0c);
    gemm_bt<true, false><<<dim3(96, 4), 256, 0, stream>>>(g0c, W1t, Wh1c, nullptr, 12288, 512, 1024);
    gat1_combine<<<2048, 256, 0, stream>>>(Wh1c, a1, featc);
    gemm_head<<<dim3(96, 2), 256, 0, stream>>>(featc, aW1t, ab1, ptypes, gc * 4, h1c);
    actor2_kernel<<<dim3(4, 32), 256, 0, stream>>>(h1c, ptypes, aW2, ab2, inputs, logits, gc * 4);
  }
  hipMemcpyAsync(hfin, h_f32, 96 * 1024 * sizeof(float), hipMemcpyDeviceToDevice, stream);
}

// Round 7
// 6007.327 us; speedup vs baseline: 4.5633x; 4.5633x over previous
//
#include <hip/hip_runtime.h>
#include <hip/hip_bf16.h>
#include <cstdint>
#include <cstddef>

// ---------- types & helpers ----------
typedef __attribute__((ext_vector_type(8))) short bf8v;   // 8 x bf16 (raw bits)
typedef __attribute__((ext_vector_type(4))) float f4v;

__device__ __forceinline__ float bf2f(unsigned short u) {
  union { unsigned int i; float f; } v; v.i = ((unsigned int)u) << 16; return v.f;
}
__device__ __forceinline__ unsigned short f2bf(float f) {
  union { float fl; unsigned int i; } v; v.fl = f;
  return (unsigned short)((v.i + 0x7FFFu + ((v.i >> 16) & 1u)) >> 16);
}
__device__ __forceinline__ void gload_lds16(const void* gsrc, void* ldst) {
  __builtin_amdgcn_global_load_lds(
      (const __attribute__((address_space(1))) unsigned int*)gsrc,
      (__attribute__((address_space(3))) unsigned int*)ldst, 16, 0, 0);
}

// ---------- prep kernels ----------
__global__ void cast_bf16_kernel(const float* __restrict__ in, unsigned short* __restrict__ out, int n) {
  int i = blockIdx.x * 256 + threadIdx.x;
  if (i < n) out[i] = f2bf(in[i]);
}

// W: [T][F][O] f32  ->  Wt: [T*O][F] bf16   (row n = t*O+o, col f)
__global__ void transpose_cast_kernel(const float* __restrict__ W, unsigned short* __restrict__ Wt,
                                      int F, int O, int n) {
  int idx = blockIdx.x * 256 + threadIdx.x;
  if (idx >= n) return;
  int f  = idx % F;
  int no = idx / F;
  int k = no / O, o = no % O;
  Wt[idx] = f2bf(W[((size_t)k * F + f) * O + o]);
}

// ---------- embedding -> emb bf16, s-major: emb[(s*96 + r)*512 + o] ----------
__global__ __launch_bounds__(256) void embed_kernel(const float* __restrict__ inp,
                                                    const int* __restrict__ ptypes,
                                                    const float* __restrict__ embW,
                                                    const float* __restrict__ embB,
                                                    unsigned short* __restrict__ emb) {
  int r = blockIdx.x;          // 0..95  (b*6 + a)
  int st = blockIdx.y;         // 0..31  (s tile of 16)
  int b = r / 6, a = r % 6;
  int t = ptypes[r];
  __shared__ float vec[16][102];
  int tid = threadIdx.x;
  for (int i = tid; i < 16 * 102; i += 256) {
    int sl = i / 102, k = i - sl * 102;
    const float* row = inp + ((size_t)(b * 512 + st * 16 + sl)) * 520;
    vec[sl][k] = (k < 72) ? row[30 + a * 73 + 1 + k] : row[k - 72];
  }
  __syncthreads();
  int o0 = tid * 2;
  float acc[16][2];
#pragma unroll
  for (int s = 0; s < 16; ++s) { acc[s][0] = 0.f; acc[s][1] = 0.f; }
  const float* W = embW + (size_t)t * 102 * 512;
  for (int k = 0; k < 102; ++k) {
    float2 w = *(const float2*)&W[k * 512 + o0];
#pragma unroll
    for (int s = 0; s < 16; ++s) {
      float v = vec[s][k];
      acc[s][0] += v * w.x; acc[s][1] += v * w.y;
    }
  }
  float b0v = embB[t * 512 + o0], b1v = embB[t * 512 + o0 + 1];
#pragma unroll
  for (int s = 0; s < 16; ++s) {
    float v0 = fmaxf(acc[s][0] + b0v, 0.f);
    float v1 = fmaxf(acc[s][1] + b1v, 0.f);
    size_t m = ((size_t)(st * 16 + s) * 96 + r) * 512 + o0;
    emb[m] = f2bf(v0); emb[m + 1] = f2bf(v1);
  }
}

// ---------- MFMA bt-GEMM: C[M,N] = A[M,K](bf16) @ B[N,K](bf16)^T (+bias) ----------
template<bool OUT_BF16, bool ADD_BIAS>
__global__ __launch_bounds__(256)
void gemm_bt(const unsigned short* __restrict__ A, const unsigned short* __restrict__ B,
             void* __restrict__ C, const float* __restrict__ bias, int M, int N, int K) {
  __shared__ __align__(16) unsigned short As[128 * 64];
  __shared__ __align__(16) unsigned short Bs[128 * 64];
  const int tid = threadIdx.x;
  const int wave = tid >> 6, lane = tid & 63;
  const int bm = blockIdx.x, bn = blockIdx.y;
  const int wm = (wave >> 1) * 64, wn = (wave & 1) * 64;
  const int lr = lane >> 3, lc = lane & 7;
  f4v acc[4][4];
#pragma unroll
  for (int i = 0; i < 4; ++i)
#pragma unroll
    for (int j = 0; j < 4; ++j) acc[i][j] = (f4v){0.f, 0.f, 0.f, 0.f};
  const unsigned short* Ab = A + (size_t)bm * 128 * K;
  const unsigned short* Bb = B + (size_t)bn * 128 * K;
  const int arow = wave * 32;

  for (int k0 = 0; k0 < K; k0 += 64) {
#pragma unroll
    for (int i = 0; i < 4; ++i) {
      int row = arow + i * 8 + lr;
      gload_lds16(Ab + (size_t)row * K + k0 + lc * 8, &As[(arow + i * 8) * 64]);
      gload_lds16(Bb + (size_t)row * K + k0 + lc * 8, &Bs[(arow + i * 8) * 64]);
    }
    __syncthreads();
#pragma unroll
    for (int kk = 0; kk < 64; kk += 32) {
      bf8v af[4], bv[4];
#pragma unroll
      for (int mi = 0; mi < 4; ++mi)
        af[mi] = *(const bf8v*)&As[(wm + mi * 16 + (lane & 15)) * 64 + kk + (lane >> 4) * 8];
#pragma unroll
      for (int ni = 0; ni < 4; ++ni)
        bv[ni] = *(const bf8v*)&Bs[(wn + ni * 16 + (lane & 15)) * 64 + kk + (lane >> 4) * 8];
#pragma unroll
      for (int mi = 0; mi < 4; ++mi)
#pragma unroll
        for (int ni = 0; ni < 4; ++ni)
          acc[mi][ni] = __builtin_amdgcn_mfma_f32_16x16x32_bf16(af[mi], bv[ni], acc[mi][ni], 0, 0, 0);
    }
    __syncthreads();
  }
  const int r0 = (lane >> 4) * 4, c0 = lane & 15;
#pragma unroll
  for (int mi = 0; mi < 4; ++mi)
#pragma unroll
    for (int ni = 0; ni < 4; ++ni) {
      int col = bn * 128 + wn + ni * 16 + c0;
      float bvv = ADD_BIAS ? bias[col] : 0.f;
#pragma unroll
      for (int j = 0; j < 4; ++j) {
        size_t row = (size_t)bm * 128 + wm + mi * 16 + r0 + j;
        float v = acc[mi][ni][j] + bvv;
        if (OUT_BF16) ((unsigned short*)C)[row * N + col] = f2bf(v);
        else          ((float*)C)[row * N + col] = v;
      }
    }
}

// ---------- persistent GRU chunk ----------
// 384 blocks x 256 threads. g = blockIdx%6 owns rows [g*16,+16); jb = blockIdx/6 owns j [jb*16,+16) x 3 gates.
// Weights pinned in VGPR (asm). h exchanged via agent-scope relaxed atomics (no fences, no L2 invalidation).
// Barrier = per-block flag array: arrival store + 64-lane vector poll (no RMW contention).
__global__ __launch_bounds__(256, 1) void gru_chunk(const unsigned short* __restrict__ Whh_bf,
                                                    const float* __restrict__ gxc,
                                                    const float* __restrict__ bhh,
                                                    unsigned short* __restrict__ h_bf,
                                                    float* __restrict__ h_f32,
                                                    unsigned short* __restrict__ gnn,
                                                    int s_base, int* __restrict__ bar) {
  const int tid = threadIdx.x, lane = tid & 63, wv = tid >> 6;
  const int g  = blockIdx.x % 6;
  const int jb = blockIdx.x / 6;
  const int j0 = jb * 16;
  const int l15 = lane & 15, lhi = lane >> 4;
  const int r0g = g * 16;

  // resident weights: 3 gates x 8 kk (B-operand rows = j0+l15), pinned via opaque asm def
  bf8v wfrag[3][8];
#pragma unroll
  for (int gg = 0; gg < 3; ++gg)
#pragma unroll
    for (int kk = 0; kk < 8; ++kk) {
      wfrag[gg][kk] = *(const bf8v*)&Whh_bf[((size_t)(gg * 1024 + j0 + l15)) * 1024 + wv * 256 + kk * 32 + lhi * 8];
      asm volatile("" : "+v"(wfrag[gg][kk]));
    }

  const int r_l = tid >> 4;     // 0..15
  const int j_l = tid & 15;
  float hreg = h_f32[(size_t)(r0g + r_l) * 1024 + j0 + j_l];
  const float bh0 = bhh[j0 + j_l], bh1 = bhh[1024 + j0 + j_l], bh2 = bhh[2048 + j0 + j_l];

  __shared__ __align__(16) float red[4][16][52];
  int* flags = bar + g * 64;

  for (int sl = 0; sl < 32; ++sl) {
    const unsigned short* hb = h_bf + (size_t)(sl & 1) * 98304;
    unsigned short* hbn      = h_bf + (size_t)((sl & 1) ^ 1) * 98304;

    // gx prefetch (L2-warm: no cache invalidation anywhere in this kernel)
    size_t gxi = ((size_t)(sl * 96 + r0g + r_l)) * 3072 + j0 + j_l;
    float xr = gxc[gxi], xz = gxc[gxi + 1024], xn = gxc[gxi + 2048];

    // A-fragments loaded coherently (agent-scope relaxed), straight into MFMA
    f4v acc0 = (f4v){0.f,0.f,0.f,0.f}, acc1 = acc0, acc2 = acc0;
    const unsigned short* hrowp = hb + (size_t)(r0g + l15) * 1024 + wv * 256 + lhi * 8;
#pragma unroll
    for (int kk = 0; kk < 8; ++kk) {
      union { unsigned long long q[2]; bf8v v; } u;
      u.q[0] = __hip_atomic_load((const unsigned long long*)(hrowp + kk * 32),
                                 __ATOMIC_RELAXED, __HIP_MEMORY_SCOPE_AGENT);
      u.q[1] = __hip_atomic_load((const unsigned long long*)(hrowp + kk * 32 + 4),
                                 __ATOMIC_RELAXED, __HIP_MEMORY_SCOPE_AGENT);
      acc0 = __builtin_amdgcn_mfma_f32_16x16x32_bf16(u.v, wfrag[0][kk], acc0, 0, 0, 0);
      acc1 = __builtin_amdgcn_mfma_f32_16x16x32_bf16(u.v, wfrag[1][kk], acc1, 0, 0, 0);
      acc2 = __builtin_amdgcn_mfma_f32_16x16x32_bf16(u.v, wfrag[2][kk], acc2, 0, 0, 0);
    }

    // K-partials to LDS: C layout row(m)=lhi*4+jj (h-row), col(n)=l15 (j)
#pragma unroll
    for (int jj = 0; jj < 4; ++jj) {
      red[wv][lhi * 4 + jj][l15]      = acc0[jj];
      red[wv][lhi * 4 + jj][16 + l15] = acc1[jj];
      red[wv][lhi * 4 + jj][32 + l15] = acc2[jj];
    }
    __syncthreads();

    float gr = red[0][r_l][j_l]      + red[1][r_l][j_l]      + red[2][r_l][j_l]      + red[3][r_l][j_l]      + bh0;
    float gz = red[0][r_l][16 + j_l] + red[1][r_l][16 + j_l] + red[2][r_l][16 + j_l] + red[3][r_l][16 + j_l] + bh1;
    float gn = red[0][r_l][32 + j_l] + red[1][r_l][32 + j_l] + red[2][r_l][32 + j_l] + red[3][r_l][32 + j_l] + bh2;
    float rg = 1.f / (1.f + expf(-(xr + gr)));
    float zg = 1.f / (1.f + expf(-(xz + gz)));
    float ng = tanhf(xn + rg * gn);
    hreg = (1.f - zg) * ng + zg * hreg;
    unsigned short hb16 = f2bf(hreg);
    int r = r0g + r_l;
    __hip_atomic_store(&hbn[(size_t)r * 1024 + j0 + j_l], hb16,
                       __ATOMIC_RELAXED, __HIP_MEMORY_SCOPE_AGENT);
    int bb = r / 6, aa = r - bb * 6;
    __builtin_nontemporal_store(hb16, &gnn[(((size_t)bb * 512 + s_base + sl) * 6 + aa) * 1024 + j0 + j_l]);

    // flag barrier: arrival = own-flag store; detection = 64-lane poll (no RMW contention)
    __syncthreads();   // all waves' coherent stores acked (vmcnt drained) before flag
    int target = s_base + sl + 1;
    if (wv == 0) {
      if (lane == 0)
        __hip_atomic_store(&flags[jb], target, __ATOMIC_RELAXED, __HIP_MEMORY_SCOPE_AGENT);
      while (__hip_atomic_load(&flags[lane], __ATOMIC_RELAXED, __HIP_MEMORY_SCOPE_AGENT) < target)
        __builtin_amdgcn_s_sleep(2);
    }
    __syncthreads();
  }

  h_f32[(size_t)(r0g + r_l) * 1024 + j0 + j_l] = hreg;
}

// ---------- GAT0 attention+combine (chunk-local bs) ----------
__global__ __launch_bounds__(256) void gat0_combine(const unsigned short* __restrict__ Wh,
                                                    const float* __restrict__ a0,
                                                    unsigned short* __restrict__ g0) {
  int bs = blockIdx.x;
  __shared__ __align__(16) float W[6][1024];
  int tid = threadIdx.x;
  const unsigned short* src = Wh + (size_t)bs * 6144;
  for (int i = tid; i < 768; i += 256) {
    bf8v v = ((const bf8v*)src)[i];
    float* dst = &W[0][0] + i * 8;
#pragma unroll
    for (int j = 0; j < 8; ++j) dst[j] = bf2f((unsigned short)v[j]);
  }
  __syncthreads();
  int k = tid >> 6, l = tid & 63;
  float ai[4], aj[4];
#pragma unroll
  for (int i = 0; i < 4; ++i) { ai[i] = a0[k * 512 + l + i * 64]; aj[i] = a0[k * 512 + 256 + l + i * 64]; }
  float ei[6], ej[6];
#pragma unroll
  for (int n = 0; n < 6; ++n) {
    float pi = 0.f, pj = 0.f;
#pragma unroll
    for (int i = 0; i < 4; ++i) { float w = W[n][k * 256 + l + i * 64]; pi += w * ai[i]; pj += w * aj[i]; }
    for (int off = 32; off; off >>= 1) { pi += __shfl_xor(pi, off); pj += __shfl_xor(pj, off); }
    ei[n] = pi; ej[n] = pj;
  }
  float attn[6][6];
#pragma unroll
  for (int n = 0; n < 6; ++n) {
    float e[6]; float mx = -1e30f;
#pragma unroll
    for (int m = 0; m < 6; ++m) { e[m] = fmaxf(ei[n] + ej[m], 0.f); mx = fmaxf(mx, e[m]); }
    float ssum = 0.f;
#pragma unroll
    for (int m = 0; m < 6; ++m) { e[m] = expf(e[m] - mx); ssum += e[m]; }
    float inv = 1.f / ssum;
#pragma unroll
    for (int m = 0; m < 6; ++m) attn[n][m] = e[m] * inv;
  }
#pragma unroll
  for (int n = 0; n < 6; ++n)
#pragma unroll
    for (int i = 0; i < 4; ++i) {
      int o = l + i * 64;
      float accv = 0.f;
#pragma unroll
      for (int m = 0; m < 6; ++m) accv += attn[n][m] * W[m][k * 256 + o];
      float v = accv > 0.f ? accv : expm1f(accv);
      g0[((size_t)bs * 6 + n) * 1024 + k * 256 + o] = f2bf(v);
    }
}

// ---------- GAT1 attention+combine, node0 only -> featc bf16 ----------
__global__ __launch_bounds__(256) void gat1_combine(const unsigned short* __restrict__ Wh,
                                                    const float* __restrict__ a1,
                                                    unsigned short* __restrict__ feat0) {
  int bs = blockIdx.x;
  __shared__ __align__(16) float W[6][512];
  int tid = threadIdx.x;
  const unsigned short* src = Wh + (size_t)bs * 3072;
  for (int i = tid; i < 384; i += 256) {
    bf8v v = ((const bf8v*)src)[i];
    float* dst = &W[0][0] + i * 8;
#pragma unroll
    for (int j = 0; j < 8; ++j) dst[j] = bf2f((unsigned short)v[j]);
  }
  __syncthreads();
  int k = tid >> 6, l = tid & 63;
  float ai[2], aj[2];
#pragma unroll
  for (int i = 0; i < 2; ++i) { ai[i] = a1[k * 256 + l + i * 64]; aj[i] = a1[k * 256 + 128 + l + i * 64]; }
  float pi = 0.f;
#pragma unroll
  for (int i = 0; i < 2; ++i) pi += W[0][k * 128 + l + i * 64] * ai[i];
  for (int off = 32; off; off >>= 1) pi += __shfl_xor(pi, off);
  float ei0 = pi;
  float ej[6];
#pragma unroll
  for (int m = 0; m < 6; ++m) {
    float pj = 0.f;
#pragma unroll
    for (int i = 0; i < 2; ++i) pj += W[m][k * 128 + l + i * 64] * aj[i];
    for (int off = 32; off; off >>= 1) pj += __shfl_xor(pj, off);
    ej[m] = pj;
  }
  float e[6]; float mx = -1e30f;
#pragma unroll
  for (int m = 0; m < 6; ++m) { e[m] = fmaxf(ei0 + ej[m], 0.f); mx = fmaxf(mx, e[m]); }
  float ssum = 0.f;
#pragma unroll
  for (int m = 0; m < 6; ++m) { e[m] = expf(e[m] - mx); ssum += e[m]; }
  float inv = 1.f / ssum;
#pragma unroll
  for (int i = 0; i < 2; ++i) {
    int o = l + i * 64;
    float accv = 0.f;
#pragma unroll
    for (int m = 0; m < 6; ++m) accv += (e[m] * inv) * W[m][k * 128 + o];
    float v = accv > 0.f ? accv : expm1f(accv);
    feat0[(size_t)bs * 512 + k * 128 + o] = f2bf(v);
  }
}

// ---------- actor GEMM1 (MFMA): h1 = relu(featc @ aW1[t0]^T + ab1[t0]) -> bf16 ----------
__global__ __launch_bounds__(256)
void gemm_head(const unsigned short* __restrict__ A, const unsigned short* __restrict__ Wt5,
               const float* __restrict__ bias5, const int* __restrict__ ptypes, int b0,
               unsigned short* __restrict__ C) {
  __shared__ __align__(16) unsigned short As[128 * 64];
  __shared__ __align__(16) unsigned short Bs[128 * 64];
  const int tid = threadIdx.x;
  const int wave = tid >> 6, lane = tid & 63;
  const int bm = blockIdx.x, bn = blockIdx.y;       // (96, 2): M=12288, N=256, K=512
  const int t0 = ptypes[(b0 + (bm >> 2)) * 6];
  const unsigned short* B = Wt5 + (size_t)t0 * 256 * 512;
  const float* bias = bias5 + t0 * 256;
  const int K = 512, N = 256;
  const int wm = (wave >> 1) * 64, wn = (wave & 1) * 64;
  const int lr = lane >> 3, lc = lane & 7;
  f4v acc[4][4];
#pragma unroll
  for (int i = 0; i < 4; ++i)
#pragma unroll
    for (int j = 0; j < 4; ++j) acc[i][j] = (f4v){0.f, 0.f, 0.f, 0.f};
  const unsigned short* Ab = A + (size_t)bm * 128 * K;
  const unsigned short* Bb = B + (size_t)bn * 128 * K;
  const int arow = wave * 32;

  for (int k0 = 0; k0 < K; k0 += 64) {
#pragma unroll
    for (int i = 0; i < 4; ++i) {
      int row = arow + i * 8 + lr;
      gload_lds16(Ab + (size_t)row * K + k0 + lc * 8, &As[(arow + i * 8) * 64]);
      gload_lds16(Bb + (size_t)row * K + k0 + lc * 8, &Bs[(arow + i * 8) * 64]);
    }
    __syncthreads();
#pragma unroll
    for (int kk = 0; kk < 64; kk += 32) {
      bf8v af[4], bv[4];
#pragma unroll
      for (int mi = 0; mi < 4; ++mi)
        af[mi] = *(const bf8v*)&As[(wm + mi * 16 + (lane & 15)) * 64 + kk + (lane >> 4) * 8];
#pragma unroll
      for (int ni = 0; ni < 4; ++ni)
        bv[ni] = *(const bf8v*)&Bs[(wn + ni * 16 + (lane & 15)) * 64 + kk + (lane >> 4) * 8];
#pragma unroll
      for (int mi = 0; mi < 4; ++mi)
#pragma unroll
        for (int ni = 0; ni < 4; ++ni)
          acc[mi][ni] = __builtin_amdgcn_mfma_f32_16x16x32_bf16(af[mi], bv[ni], acc[mi][ni], 0, 0, 0);
    }
    __syncthreads();
  }
  const int r0 = (lane >> 4) * 4, c0 = lane & 15;
#pragma unroll
  for (int mi = 0; mi < 4; ++mi)
#pragma unroll
    for (int ni = 0; ni < 4; ++ni) {
      int col = bn * 128 + wn + ni * 16 + c0;
      float bvv = bias[col];
#pragma unroll
      for (int j = 0; j < 4; ++j) {
        size_t row = (size_t)bm * 128 + wm + mi * 16 + r0 + j;
        C[row * N + col] = f2bf(fmaxf(acc[mi][ni][j] + bvv, 0.f));
      }
    }
}

// ---------- actor GEMM2: logits = h1 @ aW2[t0] + ab2[t0], masked ----------
__global__ __launch_bounds__(256) void actor2_kernel(const unsigned short* __restrict__ h1c,
                                                     const int* __restrict__ ptypes,
                                                     const float* __restrict__ aW2, const float* __restrict__ ab2,
                                                     const float* __restrict__ inp, float* __restrict__ out, int b0) {
  int bl = blockIdx.x, st = blockIdx.y;   // (4, 32)
  int b = b0 + bl;
  int t0 = ptypes[b * 6];
  __shared__ float h1[16][260];
  int tid = threadIdx.x;
  const unsigned short* src = h1c + ((size_t)bl * 512 + st * 16) * 256;
  for (int i = tid; i < 512; i += 256) {
    bf8v v = ((const bf8v*)src)[i];
    int r = (i * 8) >> 8, c = (i * 8) & 255;
#pragma unroll
    for (int j = 0; j < 8; ++j) h1[r][c + j] = bf2f((unsigned short)v[j]);
  }
  __syncthreads();
  const float* W2p = aW2 + (size_t)t0 * 256 * 52;
  for (int idx = tid; idx < 16 * 52; idx += 256) {
    int s = idx / 52, d = idx - s * 52;
    float a = ab2[t0 * 52 + d];
    for (int i = 0; i < 256; ++i) a += h1[s][i] * W2p[i * 52 + d];
    int sg = st * 16 + s;
    float m = inp[((size_t)b * 512 + sg) * 520 + 468 + d];
    out[((size_t)b * 512 + sg) * 52 + d] = (m != 0.f) ? a : 0.f;
  }
}

// ---------- launch ----------
extern "C" void kernel_launch(void* const* d_in, const int* in_sizes, int n_in,
                              void* d_out, int out_size, void* d_ws, size_t ws_size,
                              hipStream_t stream) {
  const float* inputs = (const float*)d_in[0];
  const float* state  = (const float*)d_in[1];
  const int*   ptypes = (const int*)d_in[2];
  const float* emb_W  = (const float*)d_in[3];
  const float* emb_b  = (const float*)d_in[4];
  const float* W_ih   = (const float*)d_in[5];
  const float* W_hh   = (const float*)d_in[6];
  const float* b_ih   = (const float*)d_in[7];
  const float* b_hh   = (const float*)d_in[8];
  const float* W0     = (const float*)d_in[9];
  const float* a0     = (const float*)d_in[10];
  const float* W1     = (const float*)d_in[11];
  const float* a1     = (const float*)d_in[12];
  const float* aW1    = (const float*)d_in[13];
  const float* ab1    = (const float*)d_in[14];
  const float* aW2    = (const float*)d_in[15];
  const float* ab2    = (const float*)d_in[16];

  char* ws = (char*)d_ws;
  // phase A/B (peak ~203.4 MB, proven-safe region)
  unsigned short* emb    = (unsigned short*)(ws + 0);            // 50,331,648 B  [s][r][512] bf16
  float*          gxc    = (float*)(ws + 50331648);              // 37,748,736 B  32-step chunk, f32
  unsigned short* gnn    = (unsigned short*)(ws + 88080384);     // 100,663,296 B
  float*          h_f32  = (float*)(ws + 188743680);             // 393,216 B
  unsigned short* h_bf   = (unsigned short*)(ws + 189136896);    // 393,216 B (2 bufs)
  unsigned short* Wihb   = (unsigned short*)(ws + 189530112);    // 3,145,728 B
  unsigned short* W0t    = (unsigned short*)(ws + 192675840);    // 2,097,152 B
  unsigned short* W1t    = (unsigned short*)(ws + 194772992);    // 1,048,576 B
  unsigned short* Whh_bf = (unsigned short*)(ws + 195821568);    // 6,291,456 B
  unsigned short* aW1t   = (unsigned short*)(ws + 202113024);    // 1,310,720 B
  int*            bar    = (int*)(ws + 203423744);               // 2048 B -> end 203,425,792
  // GAT-phase chunk overlays in [0, 88,080,384) (emb+gxc dead)
  unsigned short* Wh0c  = (unsigned short*)(ws + 0);             // 25,165,824 B
  unsigned short* g0c   = (unsigned short*)(ws + 25165824);      // 25,165,824 B
  unsigned short* Wh1c  = (unsigned short*)(ws + 50331648);      // 12,582,912 B
  unsigned short* featc = (unsigned short*)(ws + 62914560);      // 12,582,912 B
  unsigned short* h1c   = (unsigned short*)(ws + 75497472);      //  6,291,456 B -> end 81,788,928

  float* logits = (float*)d_out;
  float* hfin   = (float*)d_out + 16 * 512 * 52;

  // prep
  cast_bf16_kernel<<<6144, 256, 0, stream>>>(W_ih, Wihb, 3072 * 512);
  cast_bf16_kernel<<<12288, 256, 0, stream>>>(W_hh, Whh_bf, 3072 * 1024);
  transpose_cast_kernel<<<4096, 256, 0, stream>>>(W0, W0t, 1024, 256, 4 * 1024 * 256);
  transpose_cast_kernel<<<2048, 256, 0, stream>>>(W1, W1t, 1024, 128, 4 * 1024 * 128);
  transpose_cast_kernel<<<2560, 256, 0, stream>>>(aW1, aW1t, 512, 256, 5 * 256 * 512);
  cast_bf16_kernel<<<384, 256, 0, stream>>>(state, h_bf, 96 * 1024);
  hipMemcpyAsync(h_f32, state, 96 * 1024 * sizeof(float), hipMemcpyDeviceToDevice, stream);
  hipMemsetAsync(bar, 0, 2048, stream);

  embed_kernel<<<dim3(96, 32), 256, 0, stream>>>(inputs, ptypes, emb_W, emb_b, emb);

  // GRU: 16 chunks of 32 steps
  for (int c = 0; c < 16; ++c) {
    gemm_bt<false, true><<<dim3(24, 24), 256, 0, stream>>>(
        emb + (size_t)c * 3072 * 512, Wihb, gxc, b_ih, 3072, 3072, 512);
    gru_chunk<<<384, 256, 0, stream>>>(Whh_bf, gxc, b_hh, h_bf, h_f32, gnn, c * 32, bar);
  }

  // GAT + actor: 4 b-chunks of 4 batches (12288 rows)
  for (int gc = 0; gc < 4; ++gc) {
    const size_t row0 = (size_t)gc * 12288;
    gemm_bt<true, false><<<dim3(96, 8), 256, 0, stream>>>(gnn + row0 * 1024, W0t, Wh0c, nullptr, 12288, 1024, 1024);
    gat0_combine<<<2048, 256, 0, stream>>>(Wh0c, a0, g0c);
    gemm_bt<true, false><<<dim3(96, 4), 256, 0, stream>>>(g0c, W1t, Wh1c, nullptr, 12288, 512, 1024);
    gat1_combine<<<2048, 256, 0, stream>>>(Wh1c, a1, featc);
    gemm_head<<<dim3(96, 2), 256, 0, stream>>>(featc, aW1t, ab1, ptypes, gc * 4, h1c);
    actor2_kernel<<<dim3(4, 32), 256, 0, stream>>>(h1c, ptypes, aW2, ab2, inputs, logits, gc * 4);
  }
  hipMemcpyAsync(hfin, h_f32, 96 * 1024 * sizeof(float), hipMemcpyDeviceToDevice, stream);
}

// Round 9
// 4815.787 us; speedup vs baseline: 5.6923x; 1.2474x over previous
//
#include <hip/hip_runtime.h>
#include <hip/hip_bf16.h>
#include <cstdint>
#include <cstddef>

// ---------- types & helpers ----------
typedef __attribute__((ext_vector_type(8))) short bf8v;   // 8 x bf16 (raw bits)
typedef __attribute__((ext_vector_type(4))) float f4v;

__device__ __forceinline__ float bf2f(unsigned short u) {
  union { unsigned int i; float f; } v; v.i = ((unsigned int)u) << 16; return v.f;
}
__device__ __forceinline__ unsigned short f2bf(float f) {
  union { float fl; unsigned int i; } v; v.fl = f;
  return (unsigned short)((v.i + 0x7FFFu + ((v.i >> 16) & 1u)) >> 16);
}
__device__ __forceinline__ void gload_lds16(const void* gsrc, void* ldst) {
  __builtin_amdgcn_global_load_lds(
      (const __attribute__((address_space(1))) unsigned int*)gsrc,
      (__attribute__((address_space(3))) unsigned int*)ldst, 16, 0, 0);
}

// ---------- prep kernels ----------
__global__ void cast_bf16_kernel(const float* __restrict__ in, unsigned short* __restrict__ out, int n) {
  int i = blockIdx.x * 256 + threadIdx.x;
  if (i < n) out[i] = f2bf(in[i]);
}

// W: [T][F][O] f32  ->  Wt: [T*O][F] bf16   (row n = t*O+o, col f)
__global__ void transpose_cast_kernel(const float* __restrict__ W, unsigned short* __restrict__ Wt,
                                      int F, int O, int n) {
  int idx = blockIdx.x * 256 + threadIdx.x;
  if (idx >= n) return;
  int f  = idx % F;
  int no = idx / F;
  int k = no / O, o = no % O;
  Wt[idx] = f2bf(W[((size_t)k * F + f) * O + o]);
}

// init padded h_bf[2][128][1024]: padded row p = g*16+rr; valid rr<12 <- state row g*12+rr; pads zero
__global__ void init_hbf_kernel(const float* __restrict__ state, unsigned short* __restrict__ h_bf) {
  int i = blockIdx.x * 256 + threadIdx.x;      // over 128*1024
  int row = i >> 10, col = i & 1023;
  int g = row >> 4, rr = row & 15;
  unsigned short v = 0;
  if (rr < 12) v = f2bf(state[(size_t)(g * 12 + rr) * 1024 + col]);
  h_bf[i] = v;
  h_bf[131072 + i] = v;
}

// ---------- embedding -> emb bf16, s-major: emb[(s*96 + r)*512 + o] ----------
__global__ __launch_bounds__(256) void embed_kernel(const float* __restrict__ inp,
                                                    const int* __restrict__ ptypes,
                                                    const float* __restrict__ embW,
                                                    const float* __restrict__ embB,
                                                    unsigned short* __restrict__ emb) {
  int r = blockIdx.x;          // 0..95  (b*6 + a)
  int st = blockIdx.y;         // 0..31  (s tile of 16)
  int b = r / 6, a = r % 6;
  int t = ptypes[r];
  __shared__ float vec[16][102];
  int tid = threadIdx.x;
  for (int i = tid; i < 16 * 102; i += 256) {
    int sl = i / 102, k = i - sl * 102;
    const float* row = inp + ((size_t)(b * 512 + st * 16 + sl)) * 520;
    vec[sl][k] = (k < 72) ? row[30 + a * 73 + 1 + k] : row[k - 72];
  }
  __syncthreads();
  int o0 = tid * 2;
  float acc[16][2];
#pragma unroll
  for (int s = 0; s < 16; ++s) { acc[s][0] = 0.f; acc[s][1] = 0.f; }
  const float* W = embW + (size_t)t * 102 * 512;
  for (int k = 0; k < 102; ++k) {
    float2 w = *(const float2*)&W[k * 512 + o0];
#pragma unroll
    for (int s = 0; s < 16; ++s) {
      float v = vec[s][k];
      acc[s][0] += v * w.x; acc[s][1] += v * w.y;
    }
  }
  float b0v = embB[t * 512 + o0], b1v = embB[t * 512 + o0 + 1];
#pragma unroll
  for (int s = 0; s < 16; ++s) {
    float v0 = fmaxf(acc[s][0] + b0v, 0.f);
    float v1 = fmaxf(acc[s][1] + b1v, 0.f);
    size_t m = ((size_t)(st * 16 + s) * 96 + r) * 512 + o0;
    emb[m] = f2bf(v0); emb[m + 1] = f2bf(v1);
  }
}

// ---------- MFMA bt-GEMM: C[M,N] = A[M,K](bf16) @ B[N,K](bf16)^T (+bias) ----------
template<bool OUT_BF16, bool ADD_BIAS>
__global__ __launch_bounds__(256)
void gemm_bt(const unsigned short* __restrict__ A, const unsigned short* __restrict__ B,
             void* __restrict__ C, const float* __restrict__ bias, int M, int N, int K) {
  __shared__ __align__(16) unsigned short As[128 * 64];
  __shared__ __align__(16) unsigned short Bs[128 * 64];
  const int tid = threadIdx.x;
  const int wave = tid >> 6, lane = tid & 63;
  const int bm = blockIdx.x, bn = blockIdx.y;
  const int wm = (wave >> 1) * 64, wn = (wave & 1) * 64;
  const int lr = lane >> 3, lc = lane & 7;
  f4v acc[4][4];
#pragma unroll
  for (int i = 0; i < 4; ++i)
#pragma unroll
    for (int j = 0; j < 4; ++j) acc[i][j] = (f4v){0.f, 0.f, 0.f, 0.f};
  const unsigned short* Ab = A + (size_t)bm * 128 * K;
  const unsigned short* Bb = B + (size_t)bn * 128 * K;
  const int arow = wave * 32;

  for (int k0 = 0; k0 < K; k0 += 64) {
#pragma unroll
    for (int i = 0; i < 4; ++i) {
      int row = arow + i * 8 + lr;
      gload_lds16(Ab + (size_t)row * K + k0 + lc * 8, &As[(arow + i * 8) * 64]);
      gload_lds16(Bb + (size_t)row * K + k0 + lc * 8, &Bs[(arow + i * 8) * 64]);
    }
    __syncthreads();
#pragma unroll
    for (int kk = 0; kk < 64; kk += 32) {
      bf8v af[4], bv[4];
#pragma unroll
      for (int mi = 0; mi < 4; ++mi)
        af[mi] = *(const bf8v*)&As[(wm + mi * 16 + (lane & 15)) * 64 + kk + (lane >> 4) * 8];
#pragma unroll
      for (int ni = 0; ni < 4; ++ni)
        bv[ni] = *(const bf8v*)&Bs[(wn + ni * 16 + (lane & 15)) * 64 + kk + (lane >> 4) * 8];
#pragma unroll
      for (int mi = 0; mi < 4; ++mi)
#pragma unroll
        for (int ni = 0; ni < 4; ++ni)
          acc[mi][ni] = __builtin_amdgcn_mfma_f32_16x16x32_bf16(af[mi], bv[ni], acc[mi][ni], 0, 0, 0);
    }
    __syncthreads();
  }
  const int r0 = (lane >> 4) * 4, c0 = lane & 15;
#pragma unroll
  for (int mi = 0; mi < 4; ++mi)
#pragma unroll
    for (int ni = 0; ni < 4; ++ni) {
      int col = bn * 128 + wn + ni * 16 + c0;
      float bvv = ADD_BIAS ? bias[col] : 0.f;
#pragma unroll
      for (int j = 0; j < 4; ++j) {
        size_t row = (size_t)bm * 128 + wm + mi * 16 + r0 + j;
        float v = acc[mi][ni][j] + bvv;
        if (OUT_BF16) ((unsigned short*)C)[row * N + col] = f2bf(v);
        else          ((float*)C)[row * N + col] = v;
      }
    }
}

// ---------- persistent GRU chunk (XCD-local groups) ----------
// 512 blocks x 256 threads. g = blockIdx%8 (-> XCD g under round-robin dispatch) owns 12 rows [g*12,+12).
// jb = blockIdx/8 owns j [jb*16,+16) x 3 gates. Weights pinned in V/AGPRs.
// h_bf padded [2][128][1024]: group rows at g*16+0..11, pads 12..15 stay zero (MFMA-safe).
// Barrier + h exchange stay within one XCD's L2 -> ~10x lower sync latency than cross-chip.
__global__ __launch_bounds__(256, 2) void gru_chunk(const unsigned short* __restrict__ Whh_bf,
                                                    const float* __restrict__ gxc,
                                                    const float* __restrict__ bhh,
                                                    unsigned short* __restrict__ h_bf,
                                                    float* __restrict__ h_f32,
                                                    unsigned short* __restrict__ gnn,
                                                    int s_base, int* __restrict__ bar) {
  const int tid = threadIdx.x, lane = tid & 63, wv = tid >> 6;
  const int g  = blockIdx.x & 7;        // XCD-local group
  const int jb = blockIdx.x >> 3;       // 0..63 j-slice
  const int j0 = jb * 16;
  const int l15 = lane & 15, lhi = lane >> 4;
  const int rh0 = g * 16;               // padded h row base
  const int rf0 = g * 12;               // logical row base

  // resident weights: 3 gates x 8 kk (B-operand rows = j0+l15), pinned via opaque asm def
  bf8v wfrag[3][8];
#pragma unroll
  for (int gg = 0; gg < 3; ++gg)
#pragma unroll
    for (int kk = 0; kk < 8; ++kk) {
      wfrag[gg][kk] = *(const bf8v*)&Whh_bf[((size_t)(gg * 1024 + j0 + l15)) * 1024 + wv * 256 + kk * 32 + lhi * 8];
      asm volatile("" : "+v"(wfrag[gg][kk]));
    }

  const int r_l = tid >> 4;     // 0..15 (valid < 12)
  const int j_l = tid & 15;
  const bool valid = r_l < 12;
  float hreg = valid ? h_f32[(size_t)(rf0 + r_l) * 1024 + j0 + j_l] : 0.f;
  const float bh0 = bhh[j0 + j_l], bh1 = bhh[1024 + j0 + j_l], bh2 = bhh[2048 + j0 + j_l];

  __shared__ __align__(16) float red[4][16][52];
  int* flags = bar + g * 64;

  for (int sl = 0; sl < 32; ++sl) {
    const unsigned short* hb = h_bf + (size_t)(sl & 1) * 131072;
    unsigned short* hbn      = h_bf + (size_t)((sl & 1) ^ 1) * 131072;

    // gx prefetch (independent of h)
    size_t gxi = ((size_t)(sl * 96 + rf0 + r_l)) * 3072 + j0 + j_l;   // r_l>=12 reads next group's rows: valid mem, unused
    float xr = gxc[gxi], xz = gxc[gxi + 1024], xn = gxc[gxi + 2048];

    // A-fragments: coherent loads from XCD-local L2
    f4v acc0 = (f4v){0.f,0.f,0.f,0.f}, acc1 = acc0, acc2 = acc0;
    const unsigned short* hrowp = hb + (size_t)(rh0 + l15) * 1024 + wv * 256 + lhi * 8;
#pragma unroll
    for (int kk = 0; kk < 8; ++kk) {
      union { unsigned long long q[2]; bf8v v; } u;
      u.q[0] = __hip_atomic_load((const unsigned long long*)(hrowp + kk * 32),
                                 __ATOMIC_RELAXED, __HIP_MEMORY_SCOPE_AGENT);
      u.q[1] = __hip_atomic_load((const unsigned long long*)(hrowp + kk * 32 + 4),
                                 __ATOMIC_RELAXED, __HIP_MEMORY_SCOPE_AGENT);
      acc0 = __builtin_amdgcn_mfma_f32_16x16x32_bf16(u.v, wfrag[0][kk], acc0, 0, 0, 0);
      acc1 = __builtin_amdgcn_mfma_f32_16x16x32_bf16(u.v, wfrag[1][kk], acc1, 0, 0, 0);
      acc2 = __builtin_amdgcn_mfma_f32_16x16x32_bf16(u.v, wfrag[2][kk], acc2, 0, 0, 0);
    }

    // K-partials to LDS: row(m)=lhi*4+jj (h-row), col(n)=l15 (j)
#pragma unroll
    for (int jj = 0; jj < 4; ++jj) {
      red[wv][lhi * 4 + jj][l15]      = acc0[jj];
      red[wv][lhi * 4 + jj][16 + l15] = acc1[jj];
      red[wv][lhi * 4 + jj][32 + l15] = acc2[jj];
    }
    __syncthreads();

    if (valid) {
      float gr = red[0][r_l][j_l]      + red[1][r_l][j_l]      + red[2][r_l][j_l]      + red[3][r_l][j_l]      + bh0;
      float gz = red[0][r_l][16 + j_l] + red[1][r_l][16 + j_l] + red[2][r_l][16 + j_l] + red[3][r_l][16 + j_l] + bh1;
      float gn = red[0][r_l][32 + j_l] + red[1][r_l][32 + j_l] + red[2][r_l][32 + j_l] + red[3][r_l][32 + j_l] + bh2;
      float rg = 1.f / (1.f + expf(-(xr + gr)));
      float zg = 1.f / (1.f + expf(-(xz + gz)));
      float ng = tanhf(xn + rg * gn);
      hreg = (1.f - zg) * ng + zg * hreg;
      unsigned short hb16 = f2bf(hreg);
      __hip_atomic_store(&hbn[(size_t)(rh0 + r_l) * 1024 + j0 + j_l], hb16,
                         __ATOMIC_RELAXED, __HIP_MEMORY_SCOPE_AGENT);
      int r = rf0 + r_l;
      int bb = r / 6, aa = r - bb * 6;
      __builtin_nontemporal_store(hb16, &gnn[(((size_t)bb * 512 + s_base + sl) * 6 + aa) * 1024 + j0 + j_l]);
    }

    // XCD-local flag barrier: arrival = own-flag store; detection = 64-lane poll
    __syncthreads();   // drains vmcnt: h stores acked before flag store
    int target = s_base + sl + 1;
    if (wv == 0) {
      if (lane == 0)
        __hip_atomic_store(&flags[jb], target, __ATOMIC_RELAXED, __HIP_MEMORY_SCOPE_AGENT);
      while (__hip_atomic_load(&flags[lane], __ATOMIC_RELAXED, __HIP_MEMORY_SCOPE_AGENT) < target)
        __builtin_amdgcn_s_sleep(2);
    }
    __syncthreads();
  }

  if (valid) h_f32[(size_t)(rf0 + r_l) * 1024 + j0 + j_l] = hreg;
}

// ---------- GAT0 attention+combine (chunk-local bs) ----------
__global__ __launch_bounds__(256) void gat0_combine(const unsigned short* __restrict__ Wh,
                                                    const float* __restrict__ a0,
                                                    unsigned short* __restrict__ g0) {
  int bs = blockIdx.x;
  __shared__ __align__(16) float W[6][1024];
  int tid = threadIdx.x;
  const unsigned short* src = Wh + (size_t)bs * 6144;
  for (int i = tid; i < 768; i += 256) {
    bf8v v = ((const bf8v*)src)[i];
    float* dst = &W[0][0] + i * 8;
#pragma unroll
    for (int j = 0; j < 8; ++j) dst[j] = bf2f((unsigned short)v[j]);
  }
  __syncthreads();
  int k = tid >> 6, l = tid & 63;
  float ai[4], aj[4];
#pragma unroll
  for (int i = 0; i < 4; ++i) { ai[i] = a0[k * 512 + l + i * 64]; aj[i] = a0[k * 512 + 256 + l + i * 64]; }
  float ei[6], ej[6];
#pragma unroll
  for (int n = 0; n < 6; ++n) {
    float pi = 0.f, pj = 0.f;
#pragma unroll
    for (int i = 0; i < 4; ++i) { float w = W[n][k * 256 + l + i * 64]; pi += w * ai[i]; pj += w * aj[i]; }
    for (int off = 32; off; off >>= 1) { pi += __shfl_xor(pi, off); pj += __shfl_xor(pj, off); }
    ei[n] = pi; ej[n] = pj;
  }
  float attn[6][6];
#pragma unroll
  for (int n = 0; n < 6; ++n) {
    float e[6]; float mx = -1e30f;
#pragma unroll
    for (int m = 0; m < 6; ++m) { e[m] = fmaxf(ei[n] + ej[m], 0.f); mx = fmaxf(mx, e[m]); }
    float ssum = 0.f;
#pragma unroll
    for (int m = 0; m < 6; ++m) { e[m] = expf(e[m] - mx); ssum += e[m]; }
    float inv = 1.f / ssum;
#pragma unroll
    for (int m = 0; m < 6; ++m) attn[n][m] = e[m] * inv;
  }
#pragma unroll
  for (int n = 0; n < 6; ++n)
#pragma unroll
    for (int i = 0; i < 4; ++i) {
      int o = l + i * 64;
      float accv = 0.f;
#pragma unroll
      for (int m = 0; m < 6; ++m) accv += attn[n][m] * W[m][k * 256 + o];
      float v = accv > 0.f ? accv : expm1f(accv);
      g0[((size_t)bs * 6 + n) * 1024 + k * 256 + o] = f2bf(v);
    }
}

// ---------- GAT1 attention+combine, node0 only -> featc bf16 ----------
__global__ __launch_bounds__(256) void gat1_combine(const unsigned short* __restrict__ Wh,
                                                    const float* __restrict__ a1,
                                                    unsigned short* __restrict__ feat0) {
  int bs = blockIdx.x;
  __shared__ __align__(16) float W[6][512];
  int tid = threadIdx.x;
  const unsigned short* src = Wh + (size_t)bs * 3072;
  for (int i = tid; i < 384; i += 256) {
    bf8v v = ((const bf8v*)src)[i];
    float* dst = &W[0][0] + i * 8;
#pragma unroll
    for (int j = 0; j < 8; ++j) dst[j] = bf2f((unsigned short)v[j]);
  }
  __syncthreads();
  int k = tid >> 6, l = tid & 63;
  float ai[2], aj[2];
#pragma unroll
  for (int i = 0; i < 2; ++i) { ai[i] = a1[k * 256 + l + i * 64]; aj[i] = a1[k * 256 + 128 + l + i * 64]; }
  float pi = 0.f;
#pragma unroll
  for (int i = 0; i < 2; ++i) pi += W[0][k * 128 + l + i * 64] * ai[i];
  for (int off = 32; off; off >>= 1) pi += __shfl_xor(pi, off);
  float ei0 = pi;
  float ej[6];
#pragma unroll
  for (int m = 0; m < 6; ++m) {
    float pj = 0.f;
#pragma unroll
    for (int i = 0; i < 2; ++i) pj += W[m][k * 128 + l + i * 64] * aj[i];
    for (int off = 32; off; off >>= 1) pj += __shfl_xor(pj, off);
    ej[m] = pj;
  }
  float e[6]; float mx = -1e30f;
#pragma unroll
  for (int m = 0; m < 6; ++m) { e[m] = fmaxf(ei0 + ej[m], 0.f); mx = fmaxf(mx, e[m]); }
  float ssum = 0.f;
#pragma unroll
  for (int m = 0; m < 6; ++m) { e[m] = expf(e[m] - mx); ssum += e[m]; }
  float inv = 1.f / ssum;
#pragma unroll
  for (int i = 0; i < 2; ++i) {
    int o = l + i * 64;
    float accv = 0.f;
#pragma unroll
    for (int m = 0; m < 6; ++m) accv += (e[m] * inv) * W[m][k * 128 + o];
    float v = accv > 0.f ? accv : expm1f(accv);
    feat0[(size_t)bs * 512 + k * 128 + o] = f2bf(v);
  }
}

// ---------- actor GEMM1 (MFMA): h1 = relu(featc @ aW1[t0]^T + ab1[t0]) -> bf16 ----------
__global__ __launch_bounds__(256)
void gemm_head(const unsigned short* __restrict__ A, const unsigned short* __restrict__ Wt5,
               const float* __restrict__ bias5, const int* __restrict__ ptypes, int b0,
               unsigned short* __restrict__ C) {
  __shared__ __align__(16) unsigned short As[128 * 64];
  __shared__ __align__(16) unsigned short Bs[128 * 64];
  const int tid = threadIdx.x;
  const int wave = tid >> 6, lane = tid & 63;
  const int bm = blockIdx.x, bn = blockIdx.y;       // (96, 2): M=12288, N=256, K=512
  const int t0 = ptypes[(b0 + (bm >> 2)) * 6];
  const unsigned short* B = Wt5 + (size_t)t0 * 256 * 512;
  const float* bias = bias5 + t0 * 256;
  const int K = 512, N = 256;
  const int wm = (wave >> 1) * 64, wn = (wave & 1) * 64;
  const int lr = lane >> 3, lc = lane & 7;
  f4v acc[4][4];
#pragma unroll
  for (int i = 0; i < 4; ++i)
#pragma unroll
    for (int j = 0; j < 4; ++j) acc[i][j] = (f4v){0.f, 0.f, 0.f, 0.f};
  const unsigned short* Ab = A + (size_t)bm * 128 * K;
  const unsigned short* Bb = B + (size_t)bn * 128 * K;
  const int arow = wave * 32;

  for (int k0 = 0; k0 < K; k0 += 64) {
#pragma unroll
    for (int i = 0; i < 4; ++i) {
      int row = arow + i * 8 + lr;
      gload_lds16(Ab + (size_t)row * K + k0 + lc * 8, &As[(arow + i * 8) * 64]);
      gload_lds16(Bb + (size_t)row * K + k0 + lc * 8, &Bs[(arow + i * 8) * 64]);
    }
    __syncthreads();
#pragma unroll
    for (int kk = 0; kk < 64; kk += 32) {
      bf8v af[4], bv[4];
#pragma unroll
      for (int mi = 0; mi < 4; ++mi)
        af[mi] = *(const bf8v*)&As[(wm + mi * 16 + (lane & 15)) * 64 + kk + (lane >> 4) * 8];
#pragma unroll
      for (int ni = 0; ni < 4; ++ni)
        bv[ni] = *(const bf8v*)&Bs[(wn + ni * 16 + (lane & 15)) * 64 + kk + (lane >> 4) * 8];
#pragma unroll
      for (int mi = 0; mi < 4; ++mi)
#pragma unroll
        for (int ni = 0; ni < 4; ++ni)
          acc[mi][ni] = __builtin_amdgcn_mfma_f32_16x16x32_bf16(af[mi], bv[ni], acc[mi][ni], 0, 0, 0);
    }
    __syncthreads();
  }
  const int r0 = (lane >> 4) * 4, c0 = lane & 15;
#pragma unroll
  for (int mi = 0; mi < 4; ++mi)
#pragma unroll
    for (int ni = 0; ni < 4; ++ni) {
      int col = bn * 128 + wn + ni * 16 + c0;
      float bvv = bias[col];
#pragma unroll
      for (int j = 0; j < 4; ++j) {
        size_t row = (size_t)bm * 128 + wm + mi * 16 + r0 + j;
        C[row * N + col] = f2bf(fmaxf(acc[mi][ni][j] + bvv, 0.f));
      }
    }
}

// ---------- actor GEMM2: logits = h1 @ aW2[t0] + ab2[t0], masked ----------
__global__ __launch_bounds__(256) void actor2_kernel(const unsigned short* __restrict__ h1c,
                                                     const int* __restrict__ ptypes,
                                                     const float* __restrict__ aW2, const float* __restrict__ ab2,
                                                     const float* __restrict__ inp, float* __restrict__ out, int b0) {
  int bl = blockIdx.x, st = blockIdx.y;   // (4, 32)
  int b = b0 + bl;
  int t0 = ptypes[b * 6];
  __shared__ float h1[16][260];
  int tid = threadIdx.x;
  const unsigned short* src = h1c + ((size_t)bl * 512 + st * 16) * 256;
  for (int i = tid; i < 512; i += 256) {
    bf8v v = ((const bf8v*)src)[i];
    int r = (i * 8) >> 8, c = (i * 8) & 255;
#pragma unroll
    for (int j = 0; j < 8; ++j) h1[r][c + j] = bf2f((unsigned short)v[j]);
  }
  __syncthreads();
  const float* W2p = aW2 + (size_t)t0 * 256 * 52;
  for (int idx = tid; idx < 16 * 52; idx += 256) {
    int s = idx / 52, d = idx - s * 52;
    float a = ab2[t0 * 52 + d];
    for (int i = 0; i < 256; ++i) a += h1[s][i] * W2p[i * 52 + d];
    int sg = st * 16 + s;
    float m = inp[((size_t)b * 512 + sg) * 520 + 468 + d];
    out[((size_t)b * 512 + sg) * 52 + d] = (m != 0.f) ? a : 0.f;
  }
}

// ---------- launch ----------
extern "C" void kernel_launch(void* const* d_in, const int* in_sizes, int n_in,
                              void* d_out, int out_size, void* d_ws, size_t ws_size,
                              hipStream_t stream) {
  const float* inputs = (const float*)d_in[0];
  const float* state  = (const float*)d_in[1];
  const int*   ptypes = (const int*)d_in[2];
  const float* emb_W  = (const float*)d_in[3];
  const float* emb_b  = (const float*)d_in[4];
  const float* W_ih   = (const float*)d_in[5];
  const float* W_hh   = (const float*)d_in[6];
  const float* b_ih   = (const float*)d_in[7];
  const float* b_hh   = (const float*)d_in[8];
  const float* W0     = (const float*)d_in[9];
  const float* a0     = (const float*)d_in[10];
  const float* W1     = (const float*)d_in[11];
  const float* a1     = (const float*)d_in[12];
  const float* aW1    = (const float*)d_in[13];
  const float* ab1    = (const float*)d_in[14];
  const float* aW2    = (const float*)d_in[15];
  const float* ab2    = (const float*)d_in[16];

  char* ws = (char*)d_ws;
  // phase A/B (peak ~203.6 MB; round-2 proved >=233 MB safe)
  unsigned short* emb    = (unsigned short*)(ws + 0);            // 50,331,648 B  [s][r][512] bf16
  float*          gxc    = (float*)(ws + 50331648);              // 37,748,736 B  32-step chunk, f32
  unsigned short* gnn    = (unsigned short*)(ws + 88080384);     // 100,663,296 B
  float*          h_f32  = (float*)(ws + 188743680);             // 393,216 B
  unsigned short* h_bf   = (unsigned short*)(ws + 189136896);    // 524,288 B (2 x 128 x 1024, padded)
  unsigned short* Wihb   = (unsigned short*)(ws + 189661184);    // 3,145,728 B
  unsigned short* W0t    = (unsigned short*)(ws + 192806912);    // 2,097,152 B
  unsigned short* W1t    = (unsigned short*)(ws + 194904064);    // 1,048,576 B
  unsigned short* Whh_bf = (unsigned short*)(ws + 195952640);    // 6,291,456 B
  unsigned short* aW1t   = (unsigned short*)(ws + 202244096);    // 1,310,720 B
  int*            bar    = (int*)(ws + 203554816);               // 4,096 B -> end 203,558,912
  // GAT-phase chunk overlays in [0, 88,080,384) (emb+gxc dead)
  unsigned short* Wh0c  = (unsigned short*)(ws + 0);             // 25,165,824 B
  unsigned short* g0c   = (unsigned short*)(ws + 25165824);      // 25,165,824 B
  unsigned short* Wh1c  = (unsigned short*)(ws + 50331648);      // 12,582,912 B
  unsigned short* featc = (unsigned short*)(ws + 62914560);      // 12,582,912 B
  unsigned short* h1c   = (unsigned short*)(ws + 75497472);      //  6,291,456 B -> end 81,788,928

  float* logits = (float*)d_out;
  float* hfin   = (float*)d_out + 16 * 512 * 52;

  // prep
  cast_bf16_kernel<<<6144, 256, 0, stream>>>(W_ih, Wihb, 3072 * 512);
  cast_bf16_kernel<<<12288, 256, 0, stream>>>(W_hh, Whh_bf, 3072 * 1024);
  transpose_cast_kernel<<<4096, 256, 0, stream>>>(W0, W0t, 1024, 256, 4 * 1024 * 256);
  transpose_cast_kernel<<<2048, 256, 0, stream>>>(W1, W1t, 1024, 128, 4 * 1024 * 128);
  transpose_cast_kernel<<<2560, 256, 0, stream>>>(aW1, aW1t, 512, 256, 5 * 256 * 512);
  init_hbf_kernel<<<512, 256, 0, stream>>>(state, h_bf);
  hipMemcpyAsync(h_f32, state, 96 * 1024 * sizeof(float), hipMemcpyDeviceToDevice, stream);
  hipMemsetAsync(bar, 0, 4096, stream);

  embed_kernel<<<dim3(96, 32), 256, 0, stream>>>(inputs, ptypes, emb_W, emb_b, emb);

  // GRU: 16 chunks of 32 steps
  for (int c = 0; c < 16; ++c) {
    gemm_bt<false, true><<<dim3(24, 24), 256, 0, stream>>>(
        emb + (size_t)c * 3072 * 512, Wihb, gxc, b_ih, 3072, 3072, 512);
    gru_chunk<<<512, 256, 0, stream>>>(Whh_bf, gxc, b_hh, h_bf, h_f32, gnn, c * 32, bar);
  }

  // GAT + actor: 4 b-chunks of 4 batches (12288 rows)
  for (int gc = 0; gc < 4; ++gc) {
    const size_t row0 = (size_t)gc * 12288;
    gemm_bt<true, false><<<dim3(96, 8), 256, 0, stream>>>(gnn + row0 * 1024, W0t, Wh0c, nullptr, 12288, 1024, 1024);
    gat0_combine<<<2048, 256, 0, stream>>>(Wh0c, a0, g0c);
    gemm_bt<true, false><<<dim3(96, 4), 256, 0, stream>>>(g0c, W1t, Wh1c, nullptr, 12288, 512, 1024);
    gat1_combine<<<2048, 256, 0, stream>>>(Wh1c, a1, featc);
    gemm_head<<<dim3(96, 2), 256, 0, stream>>>(featc, aW1t, ab1, ptypes, gc * 4, h1c);
    actor2_kernel<<<dim3(4, 32), 256, 0, stream>>>(h1c, ptypes, aW2, ab2, inputs, logits, gc * 4);
  }
  hipMemcpyAsync(hfin, h_f32, 96 * 1024 * sizeof(float), hipMemcpyDeviceToDevice, stream);
}

// Round 10
// 4564.370 us; speedup vs baseline: 6.0059x; 1.0551x over previous
//
#include <hip/hip_runtime.h>
#include <hip/hip_bf16.h>
#include <cstdint>
#include <cstddef>

// ---------- types & helpers ----------
typedef __attribute__((ext_vector_type(8))) short bf8v;   // 8 x bf16 (raw bits)
typedef __attribute__((ext_vector_type(4))) float f4v;

__device__ __forceinline__ float bf2f(unsigned short u) {
  union { unsigned int i; float f; } v; v.i = ((unsigned int)u) << 16; return v.f;
}
__device__ __forceinline__ unsigned short f2bf(float f) {
  union { float fl; unsigned int i; } v; v.fl = f;
  return (unsigned short)((v.i + 0x7FFFu + ((v.i >> 16) & 1u)) >> 16);
}
__device__ __forceinline__ void gload_lds16(const void* gsrc, void* ldst) {
  __builtin_amdgcn_global_load_lds(
      (const __attribute__((address_space(1))) unsigned int*)gsrc,
      (__attribute__((address_space(3))) unsigned int*)ldst, 16, 0, 0);
}

// ---------- prep kernels ----------
__global__ void cast_bf16_kernel(const float* __restrict__ in, unsigned short* __restrict__ out, int n) {
  int i = blockIdx.x * 256 + threadIdx.x;
  if (i < n) out[i] = f2bf(in[i]);
}

// W: [T][F][O] f32  ->  Wt: [T*O][F] bf16   (row n = t*O+o, col f)
__global__ void transpose_cast_kernel(const float* __restrict__ W, unsigned short* __restrict__ Wt,
                                      int F, int O, int n) {
  int idx = blockIdx.x * 256 + threadIdx.x;
  if (idx >= n) return;
  int f  = idx % F;
  int no = idx / F;
  int k = no / O, o = no % O;
  Wt[idx] = f2bf(W[((size_t)k * F + f) * O + o]);
}

// init padded h_bf[2][128][1024]: padded row p = g*16+rr; valid rr<12 <- state row g*12+rr; pads zero
__global__ void init_hbf_kernel(const float* __restrict__ state, unsigned short* __restrict__ h_bf) {
  int i = blockIdx.x * 256 + threadIdx.x;      // over 128*1024
  int row = i >> 10, col = i & 1023;
  int g = row >> 4, rr = row & 15;
  unsigned short v = 0;
  if (rr < 12) v = f2bf(state[(size_t)(g * 12 + rr) * 1024 + col]);
  h_bf[i] = v;
  h_bf[131072 + i] = v;
}

// ---------- embedding -> emb bf16, s-major: emb[(s*96 + r)*512 + o] ----------
__global__ __launch_bounds__(256) void embed_kernel(const float* __restrict__ inp,
                                                    const int* __restrict__ ptypes,
                                                    const float* __restrict__ embW,
                                                    const float* __restrict__ embB,
                                                    unsigned short* __restrict__ emb) {
  int r = blockIdx.x;          // 0..95  (b*6 + a)
  int st = blockIdx.y;         // 0..31  (s tile of 16)
  int b = r / 6, a = r % 6;
  int t = ptypes[r];
  __shared__ float vec[16][102];
  int tid = threadIdx.x;
  for (int i = tid; i < 16 * 102; i += 256) {
    int sl = i / 102, k = i - sl * 102;
    const float* row = inp + ((size_t)(b * 512 + st * 16 + sl)) * 520;
    vec[sl][k] = (k < 72) ? row[30 + a * 73 + 1 + k] : row[k - 72];
  }
  __syncthreads();
  int o0 = tid * 2;
  float acc[16][2];
#pragma unroll
  for (int s = 0; s < 16; ++s) { acc[s][0] = 0.f; acc[s][1] = 0.f; }
  const float* W = embW + (size_t)t * 102 * 512;
  for (int k = 0; k < 102; ++k) {
    float2 w = *(const float2*)&W[k * 512 + o0];
#pragma unroll
    for (int s = 0; s < 16; ++s) {
      float v = vec[s][k];
      acc[s][0] += v * w.x; acc[s][1] += v * w.y;
    }
  }
  float b0v = embB[t * 512 + o0], b1v = embB[t * 512 + o0 + 1];
#pragma unroll
  for (int s = 0; s < 16; ++s) {
    float v0 = fmaxf(acc[s][0] + b0v, 0.f);
    float v1 = fmaxf(acc[s][1] + b1v, 0.f);
    size_t m = ((size_t)(st * 16 + s) * 96 + r) * 512 + o0;
    emb[m] = f2bf(v0); emb[m + 1] = f2bf(v1);
  }
}

// ---------- MFMA bt-GEMM: C[M,N] = A[M,K](bf16) @ B[N,K](bf16)^T (+bias) ----------
template<bool OUT_BF16, bool ADD_BIAS>
__global__ __launch_bounds__(256)
void gemm_bt(const unsigned short* __restrict__ A, const unsigned short* __restrict__ B,
             void* __restrict__ C, const float* __restrict__ bias, int M, int N, int K) {
  __shared__ __align__(16) unsigned short As[128 * 64];
  __shared__ __align__(16) unsigned short Bs[128 * 64];
  const int tid = threadIdx.x;
  const int wave = tid >> 6, lane = tid & 63;
  const int bm = blockIdx.x, bn = blockIdx.y;
  const int wm = (wave >> 1) * 64, wn = (wave & 1) * 64;
  const int lr = lane >> 3, lc = lane & 7;
  f4v acc[4][4];
#pragma unroll
  for (int i = 0; i < 4; ++i)
#pragma unroll
    for (int j = 0; j < 4; ++j) acc[i][j] = (f4v){0.f, 0.f, 0.f, 0.f};
  const unsigned short* Ab = A + (size_t)bm * 128 * K;
  const unsigned short* Bb = B + (size_t)bn * 128 * K;
  const int arow = wave * 32;

  for (int k0 = 0; k0 < K; k0 += 64) {
#pragma unroll
    for (int i = 0; i < 4; ++i) {
      int row = arow + i * 8 + lr;
      gload_lds16(Ab + (size_t)row * K + k0 + lc * 8, &As[(arow + i * 8) * 64]);
      gload_lds16(Bb + (size_t)row * K + k0 + lc * 8, &Bs[(arow + i * 8) * 64]);
    }
    __syncthreads();
#pragma unroll
    for (int kk = 0; kk < 64; kk += 32) {
      bf8v af[4], bv[4];
#pragma unroll
      for (int mi = 0; mi < 4; ++mi)
        af[mi] = *(const bf8v*)&As[(wm + mi * 16 + (lane & 15)) * 64 + kk + (lane >> 4) * 8];
#pragma unroll
      for (int ni = 0; ni < 4; ++ni)
        bv[ni] = *(const bf8v*)&Bs[(wn + ni * 16 + (lane & 15)) * 64 + kk + (lane >> 4) * 8];
#pragma unroll
      for (int mi = 0; mi < 4; ++mi)
#pragma unroll
        for (int ni = 0; ni < 4; ++ni)
          acc[mi][ni] = __builtin_amdgcn_mfma_f32_16x16x32_bf16(af[mi], bv[ni], acc[mi][ni], 0, 0, 0);
    }
    __syncthreads();
  }
  const int r0 = (lane >> 4) * 4, c0 = lane & 15;
#pragma unroll
  for (int mi = 0; mi < 4; ++mi)
#pragma unroll
    for (int ni = 0; ni < 4; ++ni) {
      int col = bn * 128 + wn + ni * 16 + c0;
      float bvv = ADD_BIAS ? bias[col] : 0.f;
#pragma unroll
      for (int j = 0; j < 4; ++j) {
        size_t row = (size_t)bm * 128 + wm + mi * 16 + r0 + j;
        float v = acc[mi][ni][j] + bvv;
        if (OUT_BF16) ((unsigned short*)C)[row * N + col] = f2bf(v);
        else          ((float*)C)[row * N + col] = v;
      }
    }
}

// ---------- persistent GRU chunk (XCD-local groups, release-broadcast barrier) ----------
// 512 blocks x 256 threads. g = blockIdx%8 owns 12 rows [g*12,+12); jb = blockIdx/8 owns j [jb*16,+16) x 3 gates.
// Weights pinned in V/AGPRs. h_bf padded [2][128][1024], pad rows zero.
// Barrier: arrival = 1 store/block; leader (jb==0) polls 64 flags; others poll ONE release word with ONE lane
// (kills the 4096-lane/iter poll storm). gnn store + next-gx prefetch issued into the poll window so their
// HBM latency overlaps the wait instead of sitting in the pre-flag vmcnt drain.
__global__ __launch_bounds__(256, 2) void gru_chunk(const unsigned short* __restrict__ Whh_bf,
                                                    const float* __restrict__ gxc,
                                                    const float* __restrict__ bhh,
                                                    unsigned short* __restrict__ h_bf,
                                                    float* __restrict__ h_f32,
                                                    unsigned short* __restrict__ gnn,
                                                    int s_base, int* __restrict__ bar) {
  const int tid = threadIdx.x, lane = tid & 63, wv = tid >> 6;
  const int g  = blockIdx.x & 7;        // XCD-local group
  const int jb = blockIdx.x >> 3;       // 0..63 j-slice
  const int j0 = jb * 16;
  const int l15 = lane & 15, lhi = lane >> 4;
  const int rh0 = g * 16;               // padded h row base
  const int rf0 = g * 12;               // logical row base

  // resident weights: 3 gates x 8 kk (B-operand rows = j0+l15), pinned via opaque asm def
  bf8v wfrag[3][8];
#pragma unroll
  for (int gg = 0; gg < 3; ++gg)
#pragma unroll
    for (int kk = 0; kk < 8; ++kk) {
      wfrag[gg][kk] = *(const bf8v*)&Whh_bf[((size_t)(gg * 1024 + j0 + l15)) * 1024 + wv * 256 + kk * 32 + lhi * 8];
      asm volatile("" : "+v"(wfrag[gg][kk]));
    }

  const int r_l = tid >> 4;     // 0..15 (valid < 12)
  const int j_l = tid & 15;
  const bool valid = r_l < 12;
  float hreg = valid ? h_f32[(size_t)(rf0 + r_l) * 1024 + j0 + j_l] : 0.f;
  const float bh0 = bhh[j0 + j_l], bh1 = bhh[1024 + j0 + j_l], bh2 = bhh[2048 + j0 + j_l];

  __shared__ __align__(16) float red[4][16][52];
  int* flags   = bar + g * 128;        // 64 arrival words
  int* release = bar + g * 128 + 64;   // 1 release word (own line)

  // prologue: gx for step 0
  float xr, xz, xn;
  {
    size_t gxi = ((size_t)(rf0 + r_l)) * 3072 + j0 + j_l;
    xr = gxc[gxi]; xz = gxc[gxi + 1024]; xn = gxc[gxi + 2048];
  }

  for (int sl = 0; sl < 32; ++sl) {
    const unsigned short* hb = h_bf + (size_t)(sl & 1) * 131072;
    unsigned short* hbn      = h_bf + (size_t)((sl & 1) ^ 1) * 131072;

    // A-fragments: coherent loads (XCD-local L2), straight into MFMA
    f4v acc0 = (f4v){0.f,0.f,0.f,0.f}, acc1 = acc0, acc2 = acc0;
    const unsigned short* hrowp = hb + (size_t)(rh0 + l15) * 1024 + wv * 256 + lhi * 8;
#pragma unroll
    for (int kk = 0; kk < 8; ++kk) {
      union { unsigned long long q[2]; bf8v v; } u;
      u.q[0] = __hip_atomic_load((const unsigned long long*)(hrowp + kk * 32),
                                 __ATOMIC_RELAXED, __HIP_MEMORY_SCOPE_AGENT);
      u.q[1] = __hip_atomic_load((const unsigned long long*)(hrowp + kk * 32 + 4),
                                 __ATOMIC_RELAXED, __HIP_MEMORY_SCOPE_AGENT);
      acc0 = __builtin_amdgcn_mfma_f32_16x16x32_bf16(u.v, wfrag[0][kk], acc0, 0, 0, 0);
      acc1 = __builtin_amdgcn_mfma_f32_16x16x32_bf16(u.v, wfrag[1][kk], acc1, 0, 0, 0);
      acc2 = __builtin_amdgcn_mfma_f32_16x16x32_bf16(u.v, wfrag[2][kk], acc2, 0, 0, 0);
    }

    // K-partials to LDS: row(m)=lhi*4+jj (h-row), col(n)=l15 (j)
#pragma unroll
    for (int jj = 0; jj < 4; ++jj) {
      red[wv][lhi * 4 + jj][l15]      = acc0[jj];
      red[wv][lhi * 4 + jj][16 + l15] = acc1[jj];
      red[wv][lhi * 4 + jj][32 + l15] = acc2[jj];
    }
    __syncthreads();

    unsigned short hb16 = 0;
    size_t gidx = 0;
    if (valid) {
      float gr = red[0][r_l][j_l]      + red[1][r_l][j_l]      + red[2][r_l][j_l]      + red[3][r_l][j_l]      + bh0;
      float gz = red[0][r_l][16 + j_l] + red[1][r_l][16 + j_l] + red[2][r_l][16 + j_l] + red[3][r_l][16 + j_l] + bh1;
      float gn = red[0][r_l][32 + j_l] + red[1][r_l][32 + j_l] + red[2][r_l][32 + j_l] + red[3][r_l][32 + j_l] + bh2;
      float rg = 1.f / (1.f + expf(-(xr + gr)));
      float zg = 1.f / (1.f + expf(-(xz + gz)));
      float ng = tanhf(xn + rg * gn);
      hreg = (1.f - zg) * ng + zg * hreg;
      hb16 = f2bf(hreg);
      __hip_atomic_store(&hbn[(size_t)(rh0 + r_l) * 1024 + j0 + j_l], hb16,
                         __ATOMIC_RELAXED, __HIP_MEMORY_SCOPE_AGENT);
      int r = rf0 + r_l;
      int bb = r / 6, aa = r - bb * 6;
      gidx = (((size_t)bb * 512 + s_base + sl) * 6 + aa) * 1024 + j0 + j_l;
    }

    __syncthreads();   // drains h stores (and prior gnn/gx ops) before arrival flag

    // overlap window: HBM ops issued here complete during the poll wait
    if (valid) __builtin_nontemporal_store(hb16, &gnn[gidx]);
    float nxr = 0.f, nxz = 0.f, nxn = 0.f;
    if (sl < 31) {
      size_t gxn = ((size_t)((sl + 1) * 96 + rf0 + r_l)) * 3072 + j0 + j_l;
      nxr = gxc[gxn]; nxz = gxc[gxn + 1024]; nxn = gxc[gxn + 2048];
    }

    int target = s_base + sl + 1;
    if (wv == 0) {
      if (lane == 0)
        __hip_atomic_store(&flags[jb], target, __ATOMIC_RELAXED, __HIP_MEMORY_SCOPE_AGENT);
      if (jb == 0) {
        // leader: poll the 64 arrival flags (one wave only)
        while (__hip_atomic_load(&flags[lane], __ATOMIC_RELAXED, __HIP_MEMORY_SCOPE_AGENT) < target)
          __builtin_amdgcn_s_sleep(2);
        if (lane == 0)
          __hip_atomic_store(release, target, __ATOMIC_RELAXED, __HIP_MEMORY_SCOPE_AGENT);
      } else if (lane == 0) {
        // others: single-lane poll of the broadcast release word
        while (__hip_atomic_load(release, __ATOMIC_RELAXED, __HIP_MEMORY_SCOPE_AGENT) < target)
          __builtin_amdgcn_s_sleep(2);
      }
    }
    __syncthreads();
    xr = nxr; xz = nxz; xn = nxn;
  }

  if (valid) h_f32[(size_t)(rf0 + r_l) * 1024 + j0 + j_l] = hreg;
}

// ---------- GAT0 attention+combine (chunk-local bs) ----------
__global__ __launch_bounds__(256) void gat0_combine(const unsigned short* __restrict__ Wh,
                                                    const float* __restrict__ a0,
                                                    unsigned short* __restrict__ g0) {
  int bs = blockIdx.x;
  __shared__ __align__(16) float W[6][1024];
  int tid = threadIdx.x;
  const unsigned short* src = Wh + (size_t)bs * 6144;
  for (int i = tid; i < 768; i += 256) {
    bf8v v = ((const bf8v*)src)[i];
    float* dst = &W[0][0] + i * 8;
#pragma unroll
    for (int j = 0; j < 8; ++j) dst[j] = bf2f((unsigned short)v[j]);
  }
  __syncthreads();
  int k = tid >> 6, l = tid & 63;
  float ai[4], aj[4];
#pragma unroll
  for (int i = 0; i < 4; ++i) { ai[i] = a0[k * 512 + l + i * 64]; aj[i] = a0[k * 512 + 256 + l + i * 64]; }
  float ei[6], ej[6];
#pragma unroll
  for (int n = 0; n < 6; ++n) {
    float pi = 0.f, pj = 0.f;
#pragma unroll
    for (int i = 0; i < 4; ++i) { float w = W[n][k * 256 + l + i * 64]; pi += w * ai[i]; pj += w * aj[i]; }
    for (int off = 32; off; off >>= 1) { pi += __shfl_xor(pi, off); pj += __shfl_xor(pj, off); }
    ei[n] = pi; ej[n] = pj;
  }
  float attn[6][6];
#pragma unroll
  for (int n = 0; n < 6; ++n) {
    float e[6]; float mx = -1e30f;
#pragma unroll
    for (int m = 0; m < 6; ++m) { e[m] = fmaxf(ei[n] + ej[m], 0.f); mx = fmaxf(mx, e[m]); }
    float ssum = 0.f;
#pragma unroll
    for (int m = 0; m < 6; ++m) { e[m] = expf(e[m] - mx); ssum += e[m]; }
    float inv = 1.f / ssum;
#pragma unroll
    for (int m = 0; m < 6; ++m) attn[n][m] = e[m] * inv;
  }
#pragma unroll
  for (int n = 0; n < 6; ++n)
#pragma unroll
    for (int i = 0; i < 4; ++i) {
      int o = l + i * 64;
      float accv = 0.f;
#pragma unroll
      for (int m = 0; m < 6; ++m) accv += attn[n][m] * W[m][k * 256 + o];
      float v = accv > 0.f ? accv : expm1f(accv);
      g0[((size_t)bs * 6 + n) * 1024 + k * 256 + o] = f2bf(v);
    }
}

// ---------- GAT1 attention+combine, node0 only -> featc bf16 ----------
__global__ __launch_bounds__(256) void gat1_combine(const unsigned short* __restrict__ Wh,
                                                    const float* __restrict__ a1,
                                                    unsigned short* __restrict__ feat0) {
  int bs = blockIdx.x;
  __shared__ __align__(16) float W[6][512];
  int tid = threadIdx.x;
  const unsigned short* src = Wh + (size_t)bs * 3072;
  for (int i = tid; i < 384; i += 256) {
    bf8v v = ((const bf8v*)src)[i];
    float* dst = &W[0][0] + i * 8;
#pragma unroll
    for (int j = 0; j < 8; ++j) dst[j] = bf2f((unsigned short)v[j]);
  }
  __syncthreads();
  int k = tid >> 6, l = tid & 63;
  float ai[2], aj[2];
#pragma unroll
  for (int i = 0; i < 2; ++i) { ai[i] = a1[k * 256 + l + i * 64]; aj[i] = a1[k * 256 + 128 + l + i * 64]; }
  float pi = 0.f;
#pragma unroll
  for (int i = 0; i < 2; ++i) pi += W[0][k * 128 + l + i * 64] * ai[i];
  for (int off = 32; off; off >>= 1) pi += __shfl_xor(pi, off);
  float ei0 = pi;
  float ej[6];
#pragma unroll
  for (int m = 0; m < 6; ++m) {
    float pj = 0.f;
#pragma unroll
    for (int i = 0; i < 2; ++i) pj += W[m][k * 128 + l + i * 64] * aj[i];
    for (int off = 32; off; off >>= 1) pj += __shfl_xor(pj, off);
    ej[m] = pj;
  }
  float e[6]; float mx = -1e30f;
#pragma unroll
  for (int m = 0; m < 6; ++m) { e[m] = fmaxf(ei0 + ej[m], 0.f); mx = fmaxf(mx, e[m]); }
  float ssum = 0.f;
#pragma unroll
  for (int m = 0; m < 6; ++m) { e[m] = expf(e[m] - mx); ssum += e[m]; }
  float inv = 1.f / ssum;
#pragma unroll
  for (int i = 0; i < 2; ++i) {
    int o = l + i * 64;
    float accv = 0.f;
#pragma unroll
    for (int m = 0; m < 6; ++m) accv += (e[m] * inv) * W[m][k * 128 + o];
    float v = accv > 0.f ? accv : expm1f(accv);
    feat0[(size_t)bs * 512 + k * 128 + o] = f2bf(v);
  }
}

// ---------- actor GEMM1 (MFMA): h1 = relu(featc @ aW1[t0]^T + ab1[t0]) -> bf16 ----------
__global__ __launch_bounds__(256)
void gemm_head(const unsigned short* __restrict__ A, const unsigned short* __restrict__ Wt5,
               const float* __restrict__ bias5, const int* __restrict__ ptypes, int b0,
               unsigned short* __restrict__ C) {
  __shared__ __align__(16) unsigned short As[128 * 64];
  __shared__ __align__(16) unsigned short Bs[128 * 64];
  const int tid = threadIdx.x;
  const int wave = tid >> 6, lane = tid & 63;
  const int bm = blockIdx.x, bn = blockIdx.y;       // (96, 2): M=12288, N=256, K=512
  const int t0 = ptypes[(b0 + (bm >> 2)) * 6];
  const unsigned short* B = Wt5 + (size_t)t0 * 256 * 512;
  const float* bias = bias5 + t0 * 256;
  const int K = 512, N = 256;
  const int wm = (wave >> 1) * 64, wn = (wave & 1) * 64;
  const int lr = lane >> 3, lc = lane & 7;
  f4v acc[4][4];
#pragma unroll
  for (int i = 0; i < 4; ++i)
#pragma unroll
    for (int j = 0; j < 4; ++j) acc[i][j] = (f4v){0.f, 0.f, 0.f, 0.f};
  const unsigned short* Ab = A + (size_t)bm * 128 * K;
  const unsigned short* Bb = B + (size_t)bn * 128 * K;
  const int arow = wave * 32;

  for (int k0 = 0; k0 < K; k0 += 64) {
#pragma unroll
    for (int i = 0; i < 4; ++i) {
      int row = arow + i * 8 + lr;
      gload_lds16(Ab + (size_t)row * K + k0 + lc * 8, &As[(arow + i * 8) * 64]);
      gload_lds16(Bb + (size_t)row * K + k0 + lc * 8, &Bs[(arow + i * 8) * 64]);
    }
    __syncthreads();
#pragma unroll
    for (int kk = 0; kk < 64; kk += 32) {
      bf8v af[4], bv[4];
#pragma unroll
      for (int mi = 0; mi < 4; ++mi)
        af[mi] = *(const bf8v*)&As[(wm + mi * 16 + (lane & 15)) * 64 + kk + (lane >> 4) * 8];
#pragma unroll
      for (int ni = 0; ni < 4; ++ni)
        bv[ni] = *(const bf8v*)&Bs[(wn + ni * 16 + (lane & 15)) * 64 + kk + (lane >> 4) * 8];
#pragma unroll
      for (int mi = 0; mi < 4; ++mi)
#pragma unroll
        for (int ni = 0; ni < 4; ++ni)
          acc[mi][ni] = __builtin_amdgcn_mfma_f32_16x16x32_bf16(af[mi], bv[ni], acc[mi][ni], 0, 0, 0);
    }
    __syncthreads();
  }
  const int r0 = (lane >> 4) * 4, c0 = lane & 15;
#pragma unroll
  for (int mi = 0; mi < 4; ++mi)
#pragma unroll
    for (int ni = 0; ni < 4; ++ni) {
      int col = bn * 128 + wn + ni * 16 + c0;
      float bvv = bias[col];
#pragma unroll
      for (int j = 0; j < 4; ++j) {
        size_t row = (size_t)bm * 128 + wm + mi * 16 + r0 + j;
        C[row * N + col] = f2bf(fmaxf(acc[mi][ni][j] + bvv, 0.f));
      }
    }
}

// ---------- actor GEMM2: logits = h1 @ aW2[t0] + ab2[t0], masked ----------
__global__ __launch_bounds__(256) void actor2_kernel(const unsigned short* __restrict__ h1c,
                                                     const int* __restrict__ ptypes,
                                                     const float* __restrict__ aW2, const float* __restrict__ ab2,
                                                     const float* __restrict__ inp, float* __restrict__ out, int b0) {
  int bl = blockIdx.x, st = blockIdx.y;   // (4, 32)
  int b = b0 + bl;
  int t0 = ptypes[b * 6];
  __shared__ float h1[16][260];
  int tid = threadIdx.x;
  const unsigned short* src = h1c + ((size_t)bl * 512 + st * 16) * 256;
  for (int i = tid; i < 512; i += 256) {
    bf8v v = ((const bf8v*)src)[i];
    int r = (i * 8) >> 8, c = (i * 8) & 255;
#pragma unroll
    for (int j = 0; j < 8; ++j) h1[r][c + j] = bf2f((unsigned short)v[j]);
  }
  __syncthreads();
  const float* W2p = aW2 + (size_t)t0 * 256 * 52;
  for (int idx = tid; idx < 16 * 52; idx += 256) {
    int s = idx / 52, d = idx - s * 52;
    float a = ab2[t0 * 52 + d];
    for (int i = 0; i < 256; ++i) a += h1[s][i] * W2p[i * 52 + d];
    int sg = st * 16 + s;
    float m = inp[((size_t)b * 512 + sg) * 520 + 468 + d];
    out[((size_t)b * 512 + sg) * 52 + d] = (m != 0.f) ? a : 0.f;
  }
}

// ---------- launch ----------
extern "C" void kernel_launch(void* const* d_in, const int* in_sizes, int n_in,
                              void* d_out, int out_size, void* d_ws, size_t ws_size,
                              hipStream_t stream) {
  const float* inputs = (const float*)d_in[0];
  const float* state  = (const float*)d_in[1];
  const int*   ptypes = (const int*)d_in[2];
  const float* emb_W  = (const float*)d_in[3];
  const float* emb_b  = (const float*)d_in[4];
  const float* W_ih   = (const float*)d_in[5];
  const float* W_hh   = (const float*)d_in[6];
  const float* b_ih   = (const float*)d_in[7];
  const float* b_hh   = (const float*)d_in[8];
  const float* W0     = (const float*)d_in[9];
  const float* a0     = (const float*)d_in[10];
  const float* W1     = (const float*)d_in[11];
  const float* a1     = (const float*)d_in[12];
  const float* aW1    = (const float*)d_in[13];
  const float* ab1    = (const float*)d_in[14];
  const float* aW2    = (const float*)d_in[15];
  const float* ab2    = (const float*)d_in[16];

  char* ws = (char*)d_ws;
  // phase A/B (peak ~203.6 MB; round-2 proved >=233 MB safe)
  unsigned short* emb    = (unsigned short*)(ws + 0);            // 50,331,648 B  [s][r][512] bf16
  float*          gxc    = (float*)(ws + 50331648);              // 37,748,736 B  32-step chunk, f32
  unsigned short* gnn    = (unsigned short*)(ws + 88080384);     // 100,663,296 B
  float*          h_f32  = (float*)(ws + 188743680);             // 393,216 B
  unsigned short* h_bf   = (unsigned short*)(ws + 189136896);    // 524,288 B (2 x 128 x 1024, padded)
  unsigned short* Wihb   = (unsigned short*)(ws + 189661184);    // 3,145,728 B
  unsigned short* W0t    = (unsigned short*)(ws + 192806912);    // 2,097,152 B
  unsigned short* W1t    = (unsigned short*)(ws + 194904064);    // 1,048,576 B
  unsigned short* Whh_bf = (unsigned short*)(ws + 195952640);    // 6,291,456 B
  unsigned short* aW1t   = (unsigned short*)(ws + 202244096);    // 1,310,720 B
  int*            bar    = (int*)(ws + 203554816);               // 4,096 B (8 groups x 128 ints)
  // GAT-phase chunk overlays in [0, 88,080,384) (emb+gxc dead)
  unsigned short* Wh0c  = (unsigned short*)(ws + 0);             // 25,165,824 B
  unsigned short* g0c   = (unsigned short*)(ws + 25165824);      // 25,165,824 B
  unsigned short* Wh1c  = (unsigned short*)(ws + 50331648);      // 12,582,912 B
  unsigned short* featc = (unsigned short*)(ws + 62914560);      // 12,582,912 B
  unsigned short* h1c   = (unsigned short*)(ws + 75497472);      //  6,291,456 B -> end 81,788,928

  float* logits = (float*)d_out;
  float* hfin   = (float*)d_out + 16 * 512 * 52;

  // prep
  cast_bf16_kernel<<<6144, 256, 0, stream>>>(W_ih, Wihb, 3072 * 512);
  cast_bf16_kernel<<<12288, 256, 0, stream>>>(W_hh, Whh_bf, 3072 * 1024);
  transpose_cast_kernel<<<4096, 256, 0, stream>>>(W0, W0t, 1024, 256, 4 * 1024 * 256);
  transpose_cast_kernel<<<2048, 256, 0, stream>>>(W1, W1t, 1024, 128, 4 * 1024 * 128);
  transpose_cast_kernel<<<2560, 256, 0, stream>>>(aW1, aW1t, 512, 256, 5 * 256 * 512);
  init_hbf_kernel<<<512, 256, 0, stream>>>(state, h_bf);
  hipMemcpyAsync(h_f32, state, 96 * 1024 * sizeof(float), hipMemcpyDeviceToDevice, stream);
  hipMemsetAsync(bar, 0, 4096, stream);

  embed_kernel<<<dim3(96, 32), 256, 0, stream>>>(inputs, ptypes, emb_W, emb_b, emb);

  // GRU: 16 chunks of 32 steps
  for (int c = 0; c < 16; ++c) {
    gemm_bt<false, true><<<dim3(24, 24), 256, 0, stream>>>(
        emb + (size_t)c * 3072 * 512, Wihb, gxc, b_ih, 3072, 3072, 512);
    gru_chunk<<<512, 256, 0, stream>>>(Whh_bf, gxc, b_hh, h_bf, h_f32, gnn, c * 32, bar);
  }

  // GAT + actor: 4 b-chunks of 4 batches (12288 rows)
  for (int gc = 0; gc < 4; ++gc) {
    const size_t row0 = (size_t)gc * 12288;
    gemm_bt<true, false><<<dim3(96, 8), 256, 0, stream>>>(gnn + row0 * 1024, W0t, Wh0c, nullptr, 12288, 1024, 1024);
    gat0_combine<<<2048, 256, 0, stream>>>(Wh0c, a0, g0c);
    gemm_bt<true, false><<<dim3(96, 4), 256, 0, stream>>>(g0c, W1t, Wh1c, nullptr, 12288, 512, 1024);
    gat1_combine<<<2048, 256, 0, stream>>>(Wh1c, a1, featc);
    gemm_head<<<dim3(96, 2), 256, 0, stream>>>(featc, aW1t, ab1, ptypes, gc * 4, h1c);
    actor2_kernel<<<dim3(4, 32), 256, 0, stream>>>(h1c, ptypes, aW2, ab2, inputs, logits, gc * 4);
  }
  hipMemcpyAsync(hfin, h_f32, 96 * 1024 * sizeof(float), hipMemcpyDeviceToDevice, stream);
}